// Round 1
// baseline (1587.212 us; speedup 1.0000x reference)
//
#include <hip/hip_runtime.h>
#include <math.h>

#define BN 4
#define CC 32
#define HH 64
#define WW 64
#define DD 288          // C*K*K
#define EE 144
#define NTOK 4096
#define SCALE_F 0.2357022603955158f   // 18^-0.5

// ---------------- precompute LN-folded reduction weights ----------------
// wg[l][e][d] = wr[e][d]*g[d]; wgsum[l][e] = sum_d wg; wbeta[l][e] = sum_d wr*beta + br[e]
__global__ void precompute_k(const float* __restrict__ wr0, const float* __restrict__ br0,
                             const float* __restrict__ wr1, const float* __restrict__ br1,
                             const float* __restrict__ wr2, const float* __restrict__ br2,
                             const float* __restrict__ g,  const float* __restrict__ lb,
                             float* __restrict__ wg, float* __restrict__ wgsum,
                             float* __restrict__ wbeta)
{
    int l = blockIdx.x;
    int e = threadIdx.x;            // 144 threads
    const float* wr = (l == 0) ? wr0 : ((l == 1) ? wr1 : wr2);
    const float* br = (l == 0) ? br0 : ((l == 1) ? br1 : br2);
    float sg = 0.f, sb = 0.f;
    for (int d = 0; d < DD; ++d) {
        float w = wr[e * DD + d];
        float wgv = w * g[d];
        wg[((size_t)l * EE + e) * DD + d] = wgv;
        sg += wgv;
        sb += w * lb[d];
    }
    wgsum[l * EE + e] = sg;
    wbeta[l * EE + e] = sb + br[e];
}

// ---------------- unfold + LN stats ----------------
// cols[b][c*9+i*3+j][n] = t[b][c][h+i-1][w+j-1] (0-pad); mu/rstd over D=288 per token
__global__ __launch_bounds__(256) void unfold_stats_k(const float* __restrict__ t,
    float* __restrict__ cols, float* __restrict__ mu, float* __restrict__ rstd)
{
    int blk = blockIdx.x;           // 64 = B * 16
    int b = blk >> 4, h4 = blk & 15;
    int tid = threadIdx.x;
    int h = h4 * 4 + (tid >> 6);
    int w = tid & 63;
    int n = h * 64 + w;
    float s1 = 0.f, s2 = 0.f;
    const float* tb = t + (size_t)b * CC * HH * WW;
    float* cb = cols + (size_t)b * DD * NTOK;
    for (int c = 0; c < CC; ++c) {
        const float* tc = tb + (size_t)c * HH * WW;
        #pragma unroll
        for (int i = 0; i < 3; ++i) {
            int hr = h + i - 1;
            bool rok = ((unsigned)hr < 64u);
            #pragma unroll
            for (int j = 0; j < 3; ++j) {
                int wc = w + j - 1;
                bool ok = rok && ((unsigned)wc < 64u);
                float v = ok ? tc[hr * 64 + wc] : 0.f;
                cb[(size_t)(c * 9 + i * 3 + j) * NTOK + n] = v;
                s1 += v;
                s2 = fmaf(v, v, s2);
            }
        }
    }
    float m = s1 * (1.f / 288.f);
    float var = s2 * (1.f / 288.f) - m * m;
    mu[b * NTOK + n] = m;
    rstd[b * NTOK + n] = rsqrtf(var + 1e-5f);
}

// ---------------- tiled fp32 GEMM: C[b][m][n] = sum_k A[m][k] * B[b][k][n] ----------------
// MODE 0: plain    MODE 1: LN epilogue (q0=mu,q1=rstd,q2=wgsum,q3=wbeta)
// MODE 2: +bias +resid (q2=bias, q3=resid same layout as C)
template<int MODE>
__global__ __launch_bounds__(256) void gemm_k(
    const float* __restrict__ A, const float* __restrict__ Bg, float* __restrict__ C,
    int M, int K,
    const float* __restrict__ q0, const float* __restrict__ q1,
    const float* __restrict__ q2, const float* __restrict__ q3)
{
    __shared__ float As[16][68];    // transposed A tile, padded for alignment
    __shared__ float Bs[16][128];
    int n0 = blockIdx.x * 128;
    int m0 = blockIdx.y * 64;
    int b  = blockIdx.z;
    int tid = threadIdx.x;
    const float* Bb = Bg + (size_t)b * K * NTOK;
    int la_m = tid >> 2;            // 0..63
    int la_k = (tid & 3) << 2;      // 0,4,8,12
    int lb_k = tid >> 5;            // 0..7
    int lb_n = (tid & 31) << 2;     // 0..124
    int tm = (tid >> 4) << 2;       // 0..60
    int tn = (tid & 15) << 3;       // 0..120
    float acc[4][8];
    #pragma unroll
    for (int i = 0; i < 4; ++i)
        #pragma unroll
        for (int j = 0; j < 8; ++j) acc[i][j] = 0.f;

    for (int k0 = 0; k0 < K; k0 += 16) {
        float4 av = make_float4(0.f, 0.f, 0.f, 0.f);
        if (m0 + la_m < M) av = *(const float4*)&A[(size_t)(m0 + la_m) * K + k0 + la_k];
        As[la_k + 0][la_m] = av.x;
        As[la_k + 1][la_m] = av.y;
        As[la_k + 2][la_m] = av.z;
        As[la_k + 3][la_m] = av.w;
        *(float4*)&Bs[lb_k][lb_n]     = *(const float4*)&Bb[(size_t)(k0 + lb_k) * NTOK + n0 + lb_n];
        *(float4*)&Bs[lb_k + 8][lb_n] = *(const float4*)&Bb[(size_t)(k0 + lb_k + 8) * NTOK + n0 + lb_n];
        __syncthreads();
        #pragma unroll
        for (int kk = 0; kk < 16; ++kk) {
            float4 a  = *(const float4*)&As[kk][tm];
            float4 b0 = *(const float4*)&Bs[kk][tn];
            float4 b1 = *(const float4*)&Bs[kk][tn + 4];
            float avv[4] = {a.x, a.y, a.z, a.w};
            float bvv[8] = {b0.x, b0.y, b0.z, b0.w, b1.x, b1.y, b1.z, b1.w};
            #pragma unroll
            for (int i = 0; i < 4; ++i)
                #pragma unroll
                for (int j = 0; j < 8; ++j)
                    acc[i][j] = fmaf(avv[i], bvv[j], acc[i][j]);
        }
        __syncthreads();
    }

    float muv[8], rsv[8];
    if (MODE == 1) {
        #pragma unroll
        for (int j = 0; j < 8; ++j) {
            int n = n0 + tn + j;
            muv[j] = q0[b * NTOK + n];
            rsv[j] = q1[b * NTOK + n];
        }
    }
    #pragma unroll
    for (int i = 0; i < 4; ++i) {
        int r = m0 + tm + i;
        if (r < M) {
            float* crow = C + ((size_t)b * M + r) * NTOK + n0 + tn;
            if (MODE == 0) {
                *(float4*)&crow[0] = make_float4(acc[i][0], acc[i][1], acc[i][2], acc[i][3]);
                *(float4*)&crow[4] = make_float4(acc[i][4], acc[i][5], acc[i][6], acc[i][7]);
            } else if (MODE == 1) {
                float wgs = q2[r], wb = q3[r];
                float o[8];
                #pragma unroll
                for (int j = 0; j < 8; ++j) o[j] = rsv[j] * (acc[i][j] - muv[j] * wgs) + wb;
                *(float4*)&crow[0] = make_float4(o[0], o[1], o[2], o[3]);
                *(float4*)&crow[4] = make_float4(o[4], o[5], o[6], o[7]);
            } else {
                float bias = q2[r];
                const float* rrow = q3 + ((size_t)b * M + r) * NTOK + n0 + tn;
                float4 r0 = *(const float4*)&rrow[0];
                float4 r1 = *(const float4*)&rrow[4];
                *(float4*)&crow[0] = make_float4(acc[i][0] + bias + r0.x, acc[i][1] + bias + r0.y,
                                                 acc[i][2] + bias + r0.z, acc[i][3] + bias + r0.w);
                *(float4*)&crow[4] = make_float4(acc[i][4] + bias + r1.x, acc[i][5] + bias + r1.y,
                                                 acc[i][6] + bias + r1.z, acc[i][7] + bias + r1.w);
            }
        }
    }
}

// ---------------- attention ----------------
// qkv layout (B, 432, 4096); one thread = one query row; scores are tiny -> plain exp softmax
__global__ __launch_bounds__(256) void attn_k(const float* __restrict__ qkv, float* __restrict__ o)
{
    __shared__ __align__(16) float2 Kl[256][10];   // [key][d-pair], padded row (80B, 16B-aligned)
    __shared__ __align__(16) float2 Vl[256][10];
    int quarter = blockIdx.x;       // 0..3
    int bhs = blockIdx.y;           // 0..127
    int b = bhs >> 5;
    int h = (bhs >> 2) & 7;
    int s = bhs & 3;
    int tid = threadIdx.x;
    int m = quarter * 256 + tid;
    const float* qb = qkv + (size_t)b * 432 * NTOK + s * 1024;
    float q[18];
    #pragma unroll
    for (int d = 0; d < 18; ++d)
        q[d] = qb[(size_t)(h * 18 + d) * NTOK + m] * SCALE_F;   // pre-scale q
    float2 acc[9];
    #pragma unroll
    for (int d2 = 0; d2 < 9; ++d2) acc[d2] = make_float2(0.f, 0.f);
    float l = 0.f;

    for (int c0 = 0; c0 < 1024; c0 += 256) {
        #pragma unroll
        for (int d2 = 0; d2 < 9; ++d2) {
            const float* kp = qb + (size_t)(144 + h * 18 + 2 * d2) * NTOK + c0 + tid;
            Kl[tid][d2] = make_float2(kp[0], kp[NTOK]);
            const float* vp = qb + (size_t)(288 + h * 18 + 2 * d2) * NTOK + c0 + tid;
            Vl[tid][d2] = make_float2(vp[0], vp[NTOK]);
        }
        __syncthreads();
        for (int j = 0; j < 256; ++j) {
            const float2* kr = Kl[j];       // wave-uniform -> broadcast wide ds_reads
            float sc = 0.f;
            #pragma unroll
            for (int d2 = 0; d2 < 9; ++d2) {
                float2 kk = kr[d2];
                sc = fmaf(q[2 * d2], kk.x, sc);
                sc = fmaf(q[2 * d2 + 1], kk.y, sc);
            }
            float p = __expf(sc);
            l += p;
            const float2* vr = Vl[j];
            #pragma unroll
            for (int d2 = 0; d2 < 9; ++d2) {
                float2 vv = vr[d2];
                acc[d2].x = fmaf(p, vv.x, acc[d2].x);
                acc[d2].y = fmaf(p, vv.y, acc[d2].y);
            }
        }
        __syncthreads();
    }
    float inv = 1.f / l;
    float* ob = o + (size_t)b * EE * NTOK + s * 1024;
    #pragma unroll
    for (int d2 = 0; d2 < 9; ++d2) {
        ob[(size_t)(h * 18 + 2 * d2) * NTOK + m]     = acc[d2].x * inv;
        ob[(size_t)(h * 18 + 2 * d2 + 1) * NTOK + m] = acc[d2].y * inv;
    }
}

// ---------------- fold (scatter-add of 3x3 patches, crop) ----------------
__global__ __launch_bounds__(256) void fold_k(const float* __restrict__ cols, float* __restrict__ t)
{
    int idx = blockIdx.x * 256 + threadIdx.x;     // over B*C*H*W = 524288
    int w = idx & 63;
    int h = (idx >> 6) & 63;
    int c = (idx >> 12) & 31;
    int b = idx >> 17;
    const float* cb = cols + (size_t)b * DD * NTOK + (size_t)c * 9 * NTOK;
    float sum = 0.f;
    #pragma unroll
    for (int i = 0; i < 3; ++i) {
        int hs = h + 1 - i;
        if ((unsigned)hs < 64u) {
            #pragma unroll
            for (int j = 0; j < 3; ++j) {
                int ws_ = w + 1 - j;
                if ((unsigned)ws_ < 64u)
                    sum += cb[(size_t)(i * 3 + j) * NTOK + hs * 64 + ws_];
            }
        }
    }
    t[idx] = sum;
}

// ---------------- conv3x3 + ELU + residual x ----------------
__global__ __launch_bounds__(256) void conv_k(const float* __restrict__ t,
    const float* __restrict__ cw, const float* __restrict__ cbias,
    const float* __restrict__ x, float* __restrict__ out)
{
    __shared__ float wsh[CC * 9];
    int co = blockIdx.x;
    int b  = blockIdx.y;
    int tid = threadIdx.x;
    for (int u = tid; u < CC * 9; u += 256) wsh[u] = cw[co * CC * 9 + u];
    __syncthreads();
    float bias = cbias[co];
    const float* tb = t + (size_t)b * CC * HH * WW;
    for (int p = tid; p < HH * WW; p += 256) {
        int h = p >> 6, w = p & 63;
        float acc = 0.f;
        for (int ci = 0; ci < CC; ++ci) {
            const float* tc = tb + (size_t)ci * HH * WW;
            const float* wrow = &wsh[ci * 9];
            #pragma unroll
            for (int i = 0; i < 3; ++i) {
                int hr = h + i - 1;
                if ((unsigned)hr < 64u) {
                    #pragma unroll
                    for (int j = 0; j < 3; ++j) {
                        int wc = w + j - 1;
                        if ((unsigned)wc < 64u)
                            acc = fmaf(wrow[i * 3 + j], tc[hr * 64 + wc], acc);
                    }
                }
            }
        }
        float v = acc + bias;
        float e = (v > 0.f) ? v : (__expf(v) - 1.f);
        size_t oidx = ((size_t)(b * CC + co) * HH * WW) + p;
        out[oidx] = x[oidx] + e;
    }
}

extern "C" void kernel_launch(void* const* d_in, const int* in_sizes, int n_in,
                              void* d_out, int out_size, void* d_ws, size_t ws_size,
                              hipStream_t stream)
{
    const float* x    = (const float*)d_in[0];
    const float* ln_g = (const float*)d_in[1];
    const float* ln_b = (const float*)d_in[2];
    const float* cw   = (const float*)d_in[3];
    const float* cb   = (const float*)d_in[4];
    const float* wr[3]   = {(const float*)d_in[5],  (const float*)d_in[10], (const float*)d_in[15]};
    const float* br[3]   = {(const float*)d_in[6],  (const float*)d_in[11], (const float*)d_in[16]};
    const float* wqkv[3] = {(const float*)d_in[7],  (const float*)d_in[12], (const float*)d_in[17]};
    const float* we[3]   = {(const float*)d_in[8],  (const float*)d_in[13], (const float*)d_in[18]};
    const float* be[3]   = {(const float*)d_in[9],  (const float*)d_in[14], (const float*)d_in[19]};
    float* out = (float*)d_out;

    float* p = (float*)d_ws;
    float* cols = p;  p += (size_t)BN * DD * NTOK;      // 4.7M  (raw unfold, residual source)
    float* qkv  = p;  p += (size_t)BN * 432 * NTOK;     // 7.1M  (also reused as cols_out)
    float* xr   = p;  p += (size_t)BN * EE * NTOK;      // 2.4M  (also reused as attention output o)
    float* mu   = p;  p += BN * NTOK;
    float* rstd = p;  p += BN * NTOK;
    float* tA   = p;  p += (size_t)BN * CC * HH * WW;
    float* tB   = p;  p += (size_t)BN * CC * HH * WW;
    float* wg    = p; p += (size_t)3 * EE * DD;
    float* wgsum = p; p += 3 * EE;
    float* wbeta = p; p += 3 * EE;
    (void)in_sizes; (void)n_in; (void)out_size; (void)ws_size;

    precompute_k<<<3, 144, 0, stream>>>(wr[0], br[0], wr[1], br[1], wr[2], br[2],
                                        ln_g, ln_b, wg, wgsum, wbeta);

    const float* tin = x;
    float* touts[3] = {tA, tB, tA};
    for (int l = 0; l < 3; ++l) {
        unfold_stats_k<<<64, 256, 0, stream>>>(tin, cols, mu, rstd);
        // xr[b,e,n] = rstd*(wg@cols - mu*wgsum) + wbeta
        gemm_k<1><<<dim3(32, 3, 4), 256, 0, stream>>>(wg + (size_t)l * EE * DD, cols, xr,
                                                      EE, DD, mu, rstd, wgsum + l * EE, wbeta + l * EE);
        // qkv[b,f,n] = wqkv@xr
        gemm_k<0><<<dim3(32, 7, 4), 256, 0, stream>>>(wqkv[l], xr, qkv, 432, EE,
                                                      nullptr, nullptr, nullptr, nullptr);
        // o (alias xr) = attention(qkv)
        attn_k<<<dim3(4, 128), 256, 0, stream>>>(qkv, xr);
        // cols_out (alias qkv) = we@o + be + cols
        gemm_k<2><<<dim3(32, 5, 4), 256, 0, stream>>>(we[l], xr, qkv, DD, EE,
                                                      nullptr, nullptr, be[l], cols);
        fold_k<<<2048, 256, 0, stream>>>(qkv, touts[l]);
        tin = touts[l];
    }
    conv_k<<<dim3(CC, BN), 256, 0, stream>>>(tA, cw, cb, x, out);
}

// Round 2
// 1128.506 us; speedup vs baseline: 1.4065x; 1.4065x over previous
//
#include <hip/hip_runtime.h>
#include <math.h>

#define BN 4
#define CC 32
#define HH 64
#define WW 64
#define DD 288          // C*K*K
#define EE 144
#define NTOK 4096
#define SCALE_F 0.2357022603955158f   // 18^-0.5

// ---------------- precompute LN-folded reduction weights ----------------
// wg[l][e][d] = wr[e][d]*g[d]; wgsum[l][e] = sum_d wg; wbeta[l][e] = sum_d wr*beta + br[e]
__global__ void precompute_k(const float* __restrict__ wr0, const float* __restrict__ br0,
                             const float* __restrict__ wr1, const float* __restrict__ br1,
                             const float* __restrict__ wr2, const float* __restrict__ br2,
                             const float* __restrict__ g,  const float* __restrict__ lb,
                             float* __restrict__ wg, float* __restrict__ wgsum,
                             float* __restrict__ wbeta)
{
    int l = blockIdx.x;
    int e = threadIdx.x;            // 144 threads
    const float* wr = (l == 0) ? wr0 : ((l == 1) ? wr1 : wr2);
    const float* br = (l == 0) ? br0 : ((l == 1) ? br1 : br2);
    float sg = 0.f, sb = 0.f;
    for (int d = 0; d < DD; ++d) {
        float w = wr[e * DD + d];
        float wgv = w * g[d];
        wg[((size_t)l * EE + e) * DD + d] = wgv;
        sg += wgv;
        sb += w * lb[d];
    }
    wgsum[l * EE + e] = sg;
    wbeta[l * EE + e] = sb + br[e];
}

// ---------------- unfold + LN stats ----------------
// cols[b][c*9+i*3+j][n] = t[b][c][h+i-1][w+j-1] (0-pad); mu/rstd over D=288 per token
__global__ __launch_bounds__(256) void unfold_stats_k(const float* __restrict__ t,
    float* __restrict__ cols, float* __restrict__ mu, float* __restrict__ rstd)
{
    int blk = blockIdx.x;           // 64 = B * 16
    int b = blk >> 4, h4 = blk & 15;
    int tid = threadIdx.x;
    int h = h4 * 4 + (tid >> 6);
    int w = tid & 63;
    int n = h * 64 + w;
    float s1 = 0.f, s2 = 0.f;
    const float* tb = t + (size_t)b * CC * HH * WW;
    float* cb = cols + (size_t)b * DD * NTOK;
    for (int c = 0; c < CC; ++c) {
        const float* tc = tb + (size_t)c * HH * WW;
        #pragma unroll
        for (int i = 0; i < 3; ++i) {
            int hr = h + i - 1;
            bool rok = ((unsigned)hr < 64u);
            #pragma unroll
            for (int j = 0; j < 3; ++j) {
                int wc = w + j - 1;
                bool ok = rok && ((unsigned)wc < 64u);
                float v = ok ? tc[hr * 64 + wc] : 0.f;
                cb[(size_t)(c * 9 + i * 3 + j) * NTOK + n] = v;
                s1 += v;
                s2 = fmaf(v, v, s2);
            }
        }
    }
    float m = s1 * (1.f / 288.f);
    float var = s2 * (1.f / 288.f) - m * m;
    mu[b * NTOK + n] = m;
    rstd[b * NTOK + n] = rsqrtf(var + 1e-5f);
}

// ---------------- tiled fp32 GEMM: C[b][m][n] = sum_k A[m][k] * B[b][k][n] ----------------
// MODE 0: plain    MODE 1: LN epilogue (q0=mu,q1=rstd,q2=wgsum,q3=wbeta)
// MODE 2: +bias +resid (q2=bias, q3=resid same layout as C)
template<int MODE>
__global__ __launch_bounds__(256) void gemm_k(
    const float* __restrict__ A, const float* __restrict__ Bg, float* __restrict__ C,
    int M, int K,
    const float* __restrict__ q0, const float* __restrict__ q1,
    const float* __restrict__ q2, const float* __restrict__ q3)
{
    __shared__ float As[16][68];    // transposed A tile, padded for alignment
    __shared__ float Bs[16][128];
    int n0 = blockIdx.x * 128;
    int m0 = blockIdx.y * 64;
    int b  = blockIdx.z;
    int tid = threadIdx.x;
    const float* Bb = Bg + (size_t)b * K * NTOK;
    int la_m = tid >> 2;            // 0..63
    int la_k = (tid & 3) << 2;      // 0,4,8,12
    int lb_k = tid >> 5;            // 0..7
    int lb_n = (tid & 31) << 2;     // 0..124
    int tm = (tid >> 4) << 2;       // 0..60
    int tn = (tid & 15) << 3;       // 0..120
    float acc[4][8];
    #pragma unroll
    for (int i = 0; i < 4; ++i)
        #pragma unroll
        for (int j = 0; j < 8; ++j) acc[i][j] = 0.f;

    for (int k0 = 0; k0 < K; k0 += 16) {
        float4 av = make_float4(0.f, 0.f, 0.f, 0.f);
        if (m0 + la_m < M) av = *(const float4*)&A[(size_t)(m0 + la_m) * K + k0 + la_k];
        As[la_k + 0][la_m] = av.x;
        As[la_k + 1][la_m] = av.y;
        As[la_k + 2][la_m] = av.z;
        As[la_k + 3][la_m] = av.w;
        *(float4*)&Bs[lb_k][lb_n]     = *(const float4*)&Bb[(size_t)(k0 + lb_k) * NTOK + n0 + lb_n];
        *(float4*)&Bs[lb_k + 8][lb_n] = *(const float4*)&Bb[(size_t)(k0 + lb_k + 8) * NTOK + n0 + lb_n];
        __syncthreads();
        #pragma unroll
        for (int kk = 0; kk < 16; ++kk) {
            float4 a  = *(const float4*)&As[kk][tm];
            float4 b0 = *(const float4*)&Bs[kk][tn];
            float4 b1 = *(const float4*)&Bs[kk][tn + 4];
            float avv[4] = {a.x, a.y, a.z, a.w};
            float bvv[8] = {b0.x, b0.y, b0.z, b0.w, b1.x, b1.y, b1.z, b1.w};
            #pragma unroll
            for (int i = 0; i < 4; ++i)
                #pragma unroll
                for (int j = 0; j < 8; ++j)
                    acc[i][j] = fmaf(avv[i], bvv[j], acc[i][j]);
        }
        __syncthreads();
    }

    float muv[8], rsv[8];
    if (MODE == 1) {
        #pragma unroll
        for (int j = 0; j < 8; ++j) {
            int n = n0 + tn + j;
            muv[j] = q0[b * NTOK + n];
            rsv[j] = q1[b * NTOK + n];
        }
    }
    #pragma unroll
    for (int i = 0; i < 4; ++i) {
        int r = m0 + tm + i;
        if (r < M) {
            float* crow = C + ((size_t)b * M + r) * NTOK + n0 + tn;
            if (MODE == 0) {
                *(float4*)&crow[0] = make_float4(acc[i][0], acc[i][1], acc[i][2], acc[i][3]);
                *(float4*)&crow[4] = make_float4(acc[i][4], acc[i][5], acc[i][6], acc[i][7]);
            } else if (MODE == 1) {
                float wgs = q2[r], wb = q3[r];
                float o[8];
                #pragma unroll
                for (int j = 0; j < 8; ++j) o[j] = rsv[j] * (acc[i][j] - muv[j] * wgs) + wb;
                *(float4*)&crow[0] = make_float4(o[0], o[1], o[2], o[3]);
                *(float4*)&crow[4] = make_float4(o[4], o[5], o[6], o[7]);
            } else {
                float bias = q2[r];
                const float* rrow = q3 + ((size_t)b * M + r) * NTOK + n0 + tn;
                float4 r0 = *(const float4*)&rrow[0];
                float4 r1 = *(const float4*)&rrow[4];
                *(float4*)&crow[0] = make_float4(acc[i][0] + bias + r0.x, acc[i][1] + bias + r0.y,
                                                 acc[i][2] + bias + r0.z, acc[i][3] + bias + r0.w);
                *(float4*)&crow[4] = make_float4(acc[i][4] + bias + r1.x, acc[i][5] + bias + r1.y,
                                                 acc[i][6] + bias + r1.z, acc[i][7] + bias + r1.w);
            }
        }
    }
}

// ---------------- attention ----------------
// qkv layout (B, 432, 4096); one thread = one query row; scores are tiny -> plain exp softmax
__global__ __launch_bounds__(256) void attn_k(const float* __restrict__ qkv, float* __restrict__ o)
{
    __shared__ __align__(16) float2 Kl[256][10];   // [key][d-pair], padded row (80B, 16B-aligned)
    __shared__ __align__(16) float2 Vl[256][10];
    int quarter = blockIdx.x;       // 0..3
    int bhs = blockIdx.y;           // 0..127
    int b = bhs >> 5;
    int h = (bhs >> 2) & 7;
    int s = bhs & 3;
    int tid = threadIdx.x;
    int m = quarter * 256 + tid;
    const float* qb = qkv + (size_t)b * 432 * NTOK + s * 1024;
    float q[18];
    #pragma unroll
    for (int d = 0; d < 18; ++d)
        q[d] = qb[(size_t)(h * 18 + d) * NTOK + m] * SCALE_F;   // pre-scale q
    float2 acc[9];
    #pragma unroll
    for (int d2 = 0; d2 < 9; ++d2) acc[d2] = make_float2(0.f, 0.f);
    float l = 0.f;

    for (int c0 = 0; c0 < 1024; c0 += 256) {
        #pragma unroll
        for (int d2 = 0; d2 < 9; ++d2) {
            const float* kp = qb + (size_t)(144 + h * 18 + 2 * d2) * NTOK + c0 + tid;
            Kl[tid][d2] = make_float2(kp[0], kp[NTOK]);
            const float* vp = qb + (size_t)(288 + h * 18 + 2 * d2) * NTOK + c0 + tid;
            Vl[tid][d2] = make_float2(vp[0], vp[NTOK]);
        }
        __syncthreads();
        for (int j = 0; j < 256; ++j) {
            const float2* kr = Kl[j];       // wave-uniform -> broadcast wide ds_reads
            float sc = 0.f;
            #pragma unroll
            for (int d2 = 0; d2 < 9; ++d2) {
                float2 kk = kr[d2];
                sc = fmaf(q[2 * d2], kk.x, sc);
                sc = fmaf(q[2 * d2 + 1], kk.y, sc);
            }
            float p = __expf(sc);
            l += p;
            const float2* vr = Vl[j];
            #pragma unroll
            for (int d2 = 0; d2 < 9; ++d2) {
                float2 vv = vr[d2];
                acc[d2].x = fmaf(p, vv.x, acc[d2].x);
                acc[d2].y = fmaf(p, vv.y, acc[d2].y);
            }
        }
        __syncthreads();
    }
    float inv = 1.f / l;
    float* ob = o + (size_t)b * EE * NTOK + s * 1024;
    #pragma unroll
    for (int d2 = 0; d2 < 9; ++d2) {
        ob[(size_t)(h * 18 + 2 * d2) * NTOK + m]     = acc[d2].x * inv;
        ob[(size_t)(h * 18 + 2 * d2 + 1) * NTOK + m] = acc[d2].y * inv;
    }
}

// ---------------- fold (scatter-add of 3x3 patches, crop) ----------------
__global__ __launch_bounds__(256) void fold_k(const float* __restrict__ cols, float* __restrict__ t)
{
    int idx = blockIdx.x * 256 + threadIdx.x;     // over B*C*H*W = 524288
    int w = idx & 63;
    int h = (idx >> 6) & 63;
    int c = (idx >> 12) & 31;
    int b = idx >> 17;
    const float* cb = cols + (size_t)b * DD * NTOK + (size_t)c * 9 * NTOK;
    float sum = 0.f;
    #pragma unroll
    for (int i = 0; i < 3; ++i) {
        int hs = h + 1 - i;
        if ((unsigned)hs < 64u) {
            #pragma unroll
            for (int j = 0; j < 3; ++j) {
                int ws_ = w + 1 - j;
                if ((unsigned)ws_ < 64u)
                    sum += cb[(size_t)(i * 3 + j) * NTOK + hs * 64 + ws_];
            }
        }
    }
    t[idx] = sum;
}

// ---------------- conv3x3 + ELU + residual x ----------------
// One thread per output pixel (524288 total, 2048 blocks). A 256-thread block
// covers 4 rows of one (b,co) plane -> co is block-uniform, weights in LDS.
__global__ __launch_bounds__(256) void conv_k(const float* __restrict__ t,
    const float* __restrict__ cw, const float* __restrict__ cbias,
    const float* __restrict__ x, float* __restrict__ out)
{
    __shared__ float wsh[CC * 9];
    int idx = blockIdx.x * 256 + threadIdx.x;   // b*C*H*W + co*H*W + h*W + w
    int w = idx & 63;
    int h = (idx >> 6) & 63;
    int co = (idx >> 12) & 31;
    int b = idx >> 17;
    int tid = threadIdx.x;
    for (int u = tid; u < CC * 9; u += 256) wsh[u] = cw[co * CC * 9 + u];
    __syncthreads();
    const float* tb = t + (size_t)b * CC * HH * WW;
    float acc = cbias[co];
    for (int ci = 0; ci < CC; ++ci) {
        const float* tc = tb + (size_t)ci * HH * WW;
        const float* wrow = &wsh[ci * 9];
        #pragma unroll
        for (int i = 0; i < 3; ++i) {
            int hr = h + i - 1;
            if ((unsigned)hr < 64u) {
                #pragma unroll
                for (int j = 0; j < 3; ++j) {
                    int wc = w + j - 1;
                    if ((unsigned)wc < 64u)
                        acc = fmaf(wrow[i * 3 + j], tc[hr * 64 + wc], acc);
                }
            }
        }
    }
    float e = (acc > 0.f) ? acc : (__expf(acc) - 1.f);
    out[idx] = x[idx] + e;
}

extern "C" void kernel_launch(void* const* d_in, const int* in_sizes, int n_in,
                              void* d_out, int out_size, void* d_ws, size_t ws_size,
                              hipStream_t stream)
{
    const float* x    = (const float*)d_in[0];
    const float* ln_g = (const float*)d_in[1];
    const float* ln_b = (const float*)d_in[2];
    const float* cw   = (const float*)d_in[3];
    const float* cb   = (const float*)d_in[4];
    const float* wr[3]   = {(const float*)d_in[5],  (const float*)d_in[10], (const float*)d_in[15]};
    const float* br[3]   = {(const float*)d_in[6],  (const float*)d_in[11], (const float*)d_in[16]};
    const float* wqkv[3] = {(const float*)d_in[7],  (const float*)d_in[12], (const float*)d_in[17]};
    const float* we[3]   = {(const float*)d_in[8],  (const float*)d_in[13], (const float*)d_in[18]};
    const float* be[3]   = {(const float*)d_in[9],  (const float*)d_in[14], (const float*)d_in[19]};
    float* out = (float*)d_out;

    float* p = (float*)d_ws;
    float* cols = p;  p += (size_t)BN * DD * NTOK;      // 4.7M  (raw unfold, residual source)
    float* qkv  = p;  p += (size_t)BN * 432 * NTOK;     // 7.1M  (also reused as cols_out)
    float* xr   = p;  p += (size_t)BN * EE * NTOK;      // 2.4M  (also reused as attention output o)
    float* mu   = p;  p += BN * NTOK;
    float* rstd = p;  p += BN * NTOK;
    float* tA   = p;  p += (size_t)BN * CC * HH * WW;
    float* tB   = p;  p += (size_t)BN * CC * HH * WW;
    float* wg    = p; p += (size_t)3 * EE * DD;
    float* wgsum = p; p += 3 * EE;
    float* wbeta = p; p += 3 * EE;
    (void)in_sizes; (void)n_in; (void)out_size; (void)ws_size;

    precompute_k<<<3, 144, 0, stream>>>(wr[0], br[0], wr[1], br[1], wr[2], br[2],
                                        ln_g, ln_b, wg, wgsum, wbeta);

    const float* tin = x;
    float* touts[3] = {tA, tB, tA};
    for (int l = 0; l < 3; ++l) {
        unfold_stats_k<<<64, 256, 0, stream>>>(tin, cols, mu, rstd);
        // xr[b,e,n] = rstd*(wg@cols - mu*wgsum) + wbeta
        gemm_k<1><<<dim3(32, 3, 4), 256, 0, stream>>>(wg + (size_t)l * EE * DD, cols, xr,
                                                      EE, DD, mu, rstd, wgsum + l * EE, wbeta + l * EE);
        // qkv[b,f,n] = wqkv@xr
        gemm_k<0><<<dim3(32, 7, 4), 256, 0, stream>>>(wqkv[l], xr, qkv, 432, EE,
                                                      nullptr, nullptr, nullptr, nullptr);
        // o (alias xr) = attention(qkv)
        attn_k<<<dim3(4, 128), 256, 0, stream>>>(qkv, xr);
        // cols_out (alias qkv) = we@o + be + cols
        gemm_k<2><<<dim3(32, 5, 4), 256, 0, stream>>>(we[l], xr, qkv, DD, EE,
                                                      nullptr, nullptr, be[l], cols);
        fold_k<<<2048, 256, 0, stream>>>(qkv, touts[l]);
        tin = touts[l];
    }
    conv_k<<<2048, 256, 0, stream>>>(tA, cw, cb, x, out);
}

// Round 3
// 813.321 us; speedup vs baseline: 1.9515x; 1.3875x over previous
//
#include <hip/hip_runtime.h>
#include <math.h>

#define BN 4
#define CC 32
#define HH 64
#define WW 64
#define DD 288          // C*K*K
#define EE 144
#define NTOK 4096
#define SCALE_F 0.2357022603955158f   // 18^-0.5

typedef __bf16 bf16x8 __attribute__((ext_vector_type(8)));
typedef float floatx4 __attribute__((ext_vector_type(4)));

__device__ __forceinline__ unsigned short f2bf(float x) {
    unsigned int u = __float_as_uint(x);
    u += 0x7fffu + ((u >> 16) & 1u);       // RNE
    return (unsigned short)(u >> 16);
}

// ---------------- precompute LN-folded reduction weights ----------------
__global__ void precompute_k(const float* __restrict__ wr0, const float* __restrict__ br0,
                             const float* __restrict__ wr1, const float* __restrict__ br1,
                             const float* __restrict__ wr2, const float* __restrict__ br2,
                             const float* __restrict__ g,  const float* __restrict__ lb,
                             float* __restrict__ wg, float* __restrict__ wgsum,
                             float* __restrict__ wbeta)
{
    int l = blockIdx.x;
    int e = threadIdx.x;            // 144 threads
    const float* wr = (l == 0) ? wr0 : ((l == 1) ? wr1 : wr2);
    const float* br = (l == 0) ? br0 : ((l == 1) ? br1 : br2);
    float sg = 0.f, sb = 0.f;
    for (int d = 0; d < DD; ++d) {
        float w = wr[e * DD + d];
        float wgv = w * g[d];
        wg[((size_t)l * EE + e) * DD + d] = wgv;
        sg += wgv;
        sb += w * lb[d];
    }
    wgsum[l * EE + e] = sg;
    wbeta[l * EE + e] = sb + br[e];
}

// ---------------- unfold + LN stats ----------------
__global__ __launch_bounds__(256) void unfold_stats_k(const float* __restrict__ t,
    float* __restrict__ cols, float* __restrict__ mu, float* __restrict__ rstd)
{
    int blk = blockIdx.x;           // 64 = B * 16
    int b = blk >> 4, h4 = blk & 15;
    int tid = threadIdx.x;
    int h = h4 * 4 + (tid >> 6);
    int w = tid & 63;
    int n = h * 64 + w;
    float s1 = 0.f, s2 = 0.f;
    const float* tb = t + (size_t)b * CC * HH * WW;
    float* cb = cols + (size_t)b * DD * NTOK;
    for (int c = 0; c < CC; ++c) {
        const float* tc = tb + (size_t)c * HH * WW;
        #pragma unroll
        for (int i = 0; i < 3; ++i) {
            int hr = h + i - 1;
            bool rok = ((unsigned)hr < 64u);
            #pragma unroll
            for (int j = 0; j < 3; ++j) {
                int wc = w + j - 1;
                bool ok = rok && ((unsigned)wc < 64u);
                float v = ok ? tc[hr * 64 + wc] : 0.f;
                cb[(size_t)(c * 9 + i * 3 + j) * NTOK + n] = v;
                s1 += v;
                s2 = fmaf(v, v, s2);
            }
        }
    }
    float m = s1 * (1.f / 288.f);
    float var = s2 * (1.f / 288.f) - m * m;
    mu[b * NTOK + n] = m;
    rstd[b * NTOK + n] = rsqrtf(var + 1e-5f);
}

// ---------------- tiled fp32 GEMM (unchanged) ----------------
template<int MODE>
__global__ __launch_bounds__(256) void gemm_k(
    const float* __restrict__ A, const float* __restrict__ Bg, float* __restrict__ C,
    int M, int K,
    const float* __restrict__ q0, const float* __restrict__ q1,
    const float* __restrict__ q2, const float* __restrict__ q3)
{
    __shared__ float As[16][68];
    __shared__ float Bs[16][128];
    int n0 = blockIdx.x * 128;
    int m0 = blockIdx.y * 64;
    int b  = blockIdx.z;
    int tid = threadIdx.x;
    const float* Bb = Bg + (size_t)b * K * NTOK;
    int la_m = tid >> 2;
    int la_k = (tid & 3) << 2;
    int lb_k = tid >> 5;
    int lb_n = (tid & 31) << 2;
    int tm = (tid >> 4) << 2;
    int tn = (tid & 15) << 3;
    float acc[4][8];
    #pragma unroll
    for (int i = 0; i < 4; ++i)
        #pragma unroll
        for (int j = 0; j < 8; ++j) acc[i][j] = 0.f;

    for (int k0 = 0; k0 < K; k0 += 16) {
        float4 av = make_float4(0.f, 0.f, 0.f, 0.f);
        if (m0 + la_m < M) av = *(const float4*)&A[(size_t)(m0 + la_m) * K + k0 + la_k];
        As[la_k + 0][la_m] = av.x;
        As[la_k + 1][la_m] = av.y;
        As[la_k + 2][la_m] = av.z;
        As[la_k + 3][la_m] = av.w;
        *(float4*)&Bs[lb_k][lb_n]     = *(const float4*)&Bb[(size_t)(k0 + lb_k) * NTOK + n0 + lb_n];
        *(float4*)&Bs[lb_k + 8][lb_n] = *(const float4*)&Bb[(size_t)(k0 + lb_k + 8) * NTOK + n0 + lb_n];
        __syncthreads();
        #pragma unroll
        for (int kk = 0; kk < 16; ++kk) {
            float4 a  = *(const float4*)&As[kk][tm];
            float4 b0 = *(const float4*)&Bs[kk][tn];
            float4 b1 = *(const float4*)&Bs[kk][tn + 4];
            float avv[4] = {a.x, a.y, a.z, a.w};
            float bvv[8] = {b0.x, b0.y, b0.z, b0.w, b1.x, b1.y, b1.z, b1.w};
            #pragma unroll
            for (int i = 0; i < 4; ++i)
                #pragma unroll
                for (int j = 0; j < 8; ++j)
                    acc[i][j] = fmaf(avv[i], bvv[j], acc[i][j]);
        }
        __syncthreads();
    }

    float muv[8], rsv[8];
    if (MODE == 1) {
        #pragma unroll
        for (int j = 0; j < 8; ++j) {
            int n = n0 + tn + j;
            muv[j] = q0[b * NTOK + n];
            rsv[j] = q1[b * NTOK + n];
        }
    }
    #pragma unroll
    for (int i = 0; i < 4; ++i) {
        int r = m0 + tm + i;
        if (r < M) {
            float* crow = C + ((size_t)b * M + r) * NTOK + n0 + tn;
            if (MODE == 0) {
                *(float4*)&crow[0] = make_float4(acc[i][0], acc[i][1], acc[i][2], acc[i][3]);
                *(float4*)&crow[4] = make_float4(acc[i][4], acc[i][5], acc[i][6], acc[i][7]);
            } else if (MODE == 1) {
                float wgs = q2[r], wb = q3[r];
                float o[8];
                #pragma unroll
                for (int j = 0; j < 8; ++j) o[j] = rsv[j] * (acc[i][j] - muv[j] * wgs) + wb;
                *(float4*)&crow[0] = make_float4(o[0], o[1], o[2], o[3]);
                *(float4*)&crow[4] = make_float4(o[4], o[5], o[6], o[7]);
            } else {
                float bias = q2[r];
                const float* rrow = q3 + ((size_t)b * M + r) * NTOK + n0 + tn;
                float4 r0 = *(const float4*)&rrow[0];
                float4 r1 = *(const float4*)&rrow[4];
                *(float4*)&crow[0] = make_float4(acc[i][0] + bias + r0.x, acc[i][1] + bias + r0.y,
                                                 acc[i][2] + bias + r0.z, acc[i][3] + bias + r0.w);
                *(float4*)&crow[4] = make_float4(acc[i][4] + bias + r1.x, acc[i][5] + bias + r1.y,
                                                 acc[i][6] + bias + r1.z, acc[i][7] + bias + r1.w);
            }
        }
    }
}

// ---------------- MFMA bf16 attention ----------------
// Grid: 1024 blocks = 128 (b,h,s) x 8 q-chunks of 128. 4 waves/block, wave owns 32 q.
// S^T = K·Q^T via mfma_16x16x32_bf16 (d padded to 32) -> exp -> P packed to wave-private
// LDS [q][tok] (A-layout) -> PV MFMA. V pad-row d=31 = 1.0 gives row-sum l for free.
__global__ __launch_bounds__(256) void attn_mfma_k(const float* __restrict__ qkv,
                                                   float* __restrict__ o)
{
    __shared__ short Qs[128 * 40];        // [q][d]  stride 40 bf16 (80 B)
    __shared__ short Ks[64 * 40];         // [tok][d] stride 40
    __shared__ short Vs[32 * 72];         // [d][tok] stride 72 (144 B)
    __shared__ short Ps[4 * 32 * 72];     // per-wave [q][tok] stride 72

    int blk = blockIdx.x;
    int qc  = blk & 7;
    int bhs = blk >> 3;
    int b = bhs >> 5, h = (bhs >> 2) & 7, s = bhs & 3;
    int tid  = threadIdx.x;
    int w    = tid >> 6;
    int lane = tid & 63;
    int q0 = qc * 128;

    const float* base = qkv + (size_t)b * 432 * NTOK + s * 1024;

    // ---- stage Q (pre-scaled), zero-pad d 18..31 ----
    {
        int q  = tid & 127;
        int dh = tid >> 7;                 // 0..1
        for (int d = dh; d < 18; d += 2)
            Qs[q * 40 + d] = (short)f2bf(base[(size_t)(h * 18 + d) * NTOK + q0 + q] * SCALE_F);
        for (int d = 18 + dh; d < 32; d += 2)
            Qs[q * 40 + d] = 0;
    }
    __syncthreads();

    int l15 = lane & 15, l4 = lane >> 4;
    bf16x8 qf[2];
    qf[0] = *(const bf16x8*)&Qs[(w * 32 +      l15) * 40 + l4 * 8];
    qf[1] = *(const bf16x8*)&Qs[(w * 32 + 16 + l15) * 40 + l4 * 8];

    floatx4 oacc[2][2];
    #pragma unroll
    for (int i = 0; i < 2; ++i)
        #pragma unroll
        for (int j = 0; j < 2; ++j)
            oacc[i][j] = (floatx4){0.f, 0.f, 0.f, 0.f};

    short* Pw = &Ps[w * 32 * 72];

    for (int c0 = 0; c0 < 1024; c0 += 64) {
        __syncthreads();                  // protect K/V from previous iter readers
        {
            int tok = tid & 63;
            int dh  = tid >> 6;           // 0..3
            for (int d = dh; d < 18; d += 4) {
                Ks[tok * 40 + d] = (short)f2bf(base[(size_t)(144 + h * 18 + d) * NTOK + c0 + tok]);
                Vs[d * 72 + tok] = (short)f2bf(base[(size_t)(288 + h * 18 + d) * NTOK + c0 + tok]);
            }
            for (int d = 18 + dh; d < 32; d += 4) {
                Ks[tok * 40 + d] = 0;
                Vs[d * 72 + tok] = (d == 31) ? (short)0x3F80 : (short)0;   // bf16 1.0
            }
        }
        __syncthreads();

        // S^T tiles: m = token (4 tiles), n = q (2 tiles), one K-step (d=32)
        bf16x8 kf[4];
        #pragma unroll
        for (int mi = 0; mi < 4; ++mi)
            kf[mi] = *(const bf16x8*)&Ks[(mi * 16 + l15) * 40 + l4 * 8];

        floatx4 sacc[4][2];
        #pragma unroll
        for (int mi = 0; mi < 4; ++mi)
            #pragma unroll
            for (int ni = 0; ni < 2; ++ni) {
                floatx4 z = (floatx4){0.f, 0.f, 0.f, 0.f};
                sacc[mi][ni] = __builtin_amdgcn_mfma_f32_16x16x32_bf16(kf[mi], qf[ni], z, 0, 0, 0);
            }

        // exp + pack 4 consecutive tokens -> one b64 write into wave-private P [q][tok]
        #pragma unroll
        for (int mi = 0; mi < 4; ++mi)
            #pragma unroll
            for (int ni = 0; ni < 2; ++ni) {
                int ql   = ni * 16 + l15;          // q within wave
                int tokb = mi * 16 + l4 * 4;       // 4 consecutive tokens
                ushort4 pk;
                pk.x = f2bf(__expf(sacc[mi][ni][0]));
                pk.y = f2bf(__expf(sacc[mi][ni][1]));
                pk.z = f2bf(__expf(sacc[mi][ni][2]));
                pk.w = f2bf(__expf(sacc[mi][ni][3]));
                *(ushort4*)&Pw[ql * 72 + tokb] = pk;
            }
        // wave-private round trip: no barrier needed (in-order LDS pipe per wave)

        // PV: m = q (2 tiles), n = d (2 tiles), k = token (2 steps of 32)
        #pragma unroll
        for (int ks = 0; ks < 2; ++ks) {
            bf16x8 pf[2], vf[2];
            pf[0] = *(const bf16x8*)&Pw[(     l15) * 72 + ks * 32 + l4 * 8];
            pf[1] = *(const bf16x8*)&Pw[(16 + l15) * 72 + ks * 32 + l4 * 8];
            vf[0] = *(const bf16x8*)&Vs[(     l15) * 72 + ks * 32 + l4 * 8];
            vf[1] = *(const bf16x8*)&Vs[(16 + l15) * 72 + ks * 32 + l4 * 8];
            #pragma unroll
            for (int mi = 0; mi < 2; ++mi)
                #pragma unroll
                for (int nd = 0; nd < 2; ++nd)
                    oacc[mi][nd] = __builtin_amdgcn_mfma_f32_16x16x32_bf16(pf[mi], vf[nd], oacc[mi][nd], 0, 0, 0);
        }
    }

    // normalize by l (= O col d=31) and transpose through dead P region
    float* fO = (float*)Pw;               // 32 x 33 f32 = 4224 B <= 4608 B
    #pragma unroll
    for (int mi = 0; mi < 2; ++mi)
        #pragma unroll
        for (int r = 0; r < 4; ++r) {
            float lsum = __shfl(oacc[mi][1][r], (lane & 48) | 15, 64);
            float inv  = 1.f / lsum;
            int ql = mi * 16 + l4 * 4 + r;
            fO[ql * 33 + l15] = oacc[mi][0][r] * inv;
            if (l15 < 2) fO[ql * 33 + 16 + l15] = oacc[mi][1][r] * inv;
        }

    {
        int q  = lane & 31;
        int dh = lane >> 5;               // 0..1
        float* ob = o + (size_t)b * EE * NTOK + s * 1024 + q0 + w * 32;
        for (int d = dh; d < 18; d += 2)
            ob[(size_t)(h * 18 + d) * NTOK + q] = fO[q * 33 + d];
    }
}

// ---------------- fold ----------------
__global__ __launch_bounds__(256) void fold_k(const float* __restrict__ cols, float* __restrict__ t)
{
    int idx = blockIdx.x * 256 + threadIdx.x;
    int w = idx & 63;
    int h = (idx >> 6) & 63;
    int c = (idx >> 12) & 31;
    int b = idx >> 17;
    const float* cb = cols + (size_t)b * DD * NTOK + (size_t)c * 9 * NTOK;
    float sum = 0.f;
    #pragma unroll
    for (int i = 0; i < 3; ++i) {
        int hs = h + 1 - i;
        if ((unsigned)hs < 64u) {
            #pragma unroll
            for (int j = 0; j < 3; ++j) {
                int ws_ = w + 1 - j;
                if ((unsigned)ws_ < 64u)
                    sum += cb[(size_t)(i * 3 + j) * NTOK + hs * 64 + ws_];
            }
        }
    }
    t[idx] = sum;
}

// ---------------- conv3x3 + ELU + residual ----------------
__global__ __launch_bounds__(256) void conv_k(const float* __restrict__ t,
    const float* __restrict__ cw, const float* __restrict__ cbias,
    const float* __restrict__ x, float* __restrict__ out)
{
    __shared__ float wsh[CC * 9];
    int idx = blockIdx.x * 256 + threadIdx.x;
    int w = idx & 63;
    int h = (idx >> 6) & 63;
    int co = (idx >> 12) & 31;
    int b = idx >> 17;
    int tid = threadIdx.x;
    for (int u = tid; u < CC * 9; u += 256) wsh[u] = cw[co * CC * 9 + u];
    __syncthreads();
    const float* tb = t + (size_t)b * CC * HH * WW;
    float acc = cbias[co];
    for (int ci = 0; ci < CC; ++ci) {
        const float* tc = tb + (size_t)ci * HH * WW;
        const float* wrow = &wsh[ci * 9];
        #pragma unroll
        for (int i = 0; i < 3; ++i) {
            int hr = h + i - 1;
            if ((unsigned)hr < 64u) {
                #pragma unroll
                for (int j = 0; j < 3; ++j) {
                    int wc = w + j - 1;
                    if ((unsigned)wc < 64u)
                        acc = fmaf(wrow[i * 3 + j], tc[hr * 64 + wc], acc);
                }
            }
        }
    }
    float e = (acc > 0.f) ? acc : (__expf(acc) - 1.f);
    out[idx] = x[idx] + e;
}

extern "C" void kernel_launch(void* const* d_in, const int* in_sizes, int n_in,
                              void* d_out, int out_size, void* d_ws, size_t ws_size,
                              hipStream_t stream)
{
    const float* x    = (const float*)d_in[0];
    const float* ln_g = (const float*)d_in[1];
    const float* ln_b = (const float*)d_in[2];
    const float* cw   = (const float*)d_in[3];
    const float* cb   = (const float*)d_in[4];
    const float* wr[3]   = {(const float*)d_in[5],  (const float*)d_in[10], (const float*)d_in[15]};
    const float* br[3]   = {(const float*)d_in[6],  (const float*)d_in[11], (const float*)d_in[16]};
    const float* wqkv[3] = {(const float*)d_in[7],  (const float*)d_in[12], (const float*)d_in[17]};
    const float* we[3]   = {(const float*)d_in[8],  (const float*)d_in[13], (const float*)d_in[18]};
    const float* be[3]   = {(const float*)d_in[9],  (const float*)d_in[14], (const float*)d_in[19]};
    float* out = (float*)d_out;

    float* p = (float*)d_ws;
    float* cols = p;  p += (size_t)BN * DD * NTOK;
    float* qkv  = p;  p += (size_t)BN * 432 * NTOK;
    float* xr   = p;  p += (size_t)BN * EE * NTOK;
    float* mu   = p;  p += BN * NTOK;
    float* rstd = p;  p += BN * NTOK;
    float* tA   = p;  p += (size_t)BN * CC * HH * WW;
    float* tB   = p;  p += (size_t)BN * CC * HH * WW;
    float* wg    = p; p += (size_t)3 * EE * DD;
    float* wgsum = p; p += 3 * EE;
    float* wbeta = p; p += 3 * EE;
    (void)in_sizes; (void)n_in; (void)out_size; (void)ws_size;

    precompute_k<<<3, 144, 0, stream>>>(wr[0], br[0], wr[1], br[1], wr[2], br[2],
                                        ln_g, ln_b, wg, wgsum, wbeta);

    const float* tin = x;
    float* touts[3] = {tA, tB, tA};
    for (int l = 0; l < 3; ++l) {
        unfold_stats_k<<<64, 256, 0, stream>>>(tin, cols, mu, rstd);
        gemm_k<1><<<dim3(32, 3, 4), 256, 0, stream>>>(wg + (size_t)l * EE * DD, cols, xr,
                                                      EE, DD, mu, rstd, wgsum + l * EE, wbeta + l * EE);
        gemm_k<0><<<dim3(32, 7, 4), 256, 0, stream>>>(wqkv[l], xr, qkv, 432, EE,
                                                      nullptr, nullptr, nullptr, nullptr);
        attn_mfma_k<<<1024, 256, 0, stream>>>(qkv, xr);
        gemm_k<2><<<dim3(32, 5, 4), 256, 0, stream>>>(we[l], xr, qkv, DD, EE,
                                                      nullptr, nullptr, be[l], cols);
        fold_k<<<2048, 256, 0, stream>>>(qkv, touts[l]);
        tin = touts[l];
    }
    conv_k<<<2048, 256, 0, stream>>>(tA, cw, cb, x, out);
}

// Round 4
// 536.586 us; speedup vs baseline: 2.9580x; 1.5157x over previous
//
#include <hip/hip_runtime.h>
#include <math.h>

#define BN 4
#define CC 32
#define HH 64
#define WW 64
#define DD 288          // C*K*K
#define EE 144
#define NTOK 4096
#define SCALE_F 0.2357022603955158f           // 18^-0.5
#define QSCALE  0.3401074286f                 // SCALE_F * log2(e)

typedef __bf16 bf16x8 __attribute__((ext_vector_type(8)));
typedef float floatx4 __attribute__((ext_vector_type(4)));
typedef unsigned short u16x8 __attribute__((ext_vector_type(8)));
typedef unsigned short ushort_t;

__device__ __forceinline__ unsigned short f2bf(float x) {
    unsigned int u = __float_as_uint(x);
    u += 0x7fffu + ((u >> 16) & 1u);          // RNE
    return (unsigned short)(u >> 16);
}
__device__ __forceinline__ float bf2f(unsigned short s) {
    return __uint_as_float(((unsigned int)s) << 16);
}

// ---------------- precompute LN-folded reduction weights (bf16) ----------------
__global__ void precompute_k(const float* __restrict__ wr0, const float* __restrict__ br0,
                             const float* __restrict__ wr1, const float* __restrict__ br1,
                             const float* __restrict__ wr2, const float* __restrict__ br2,
                             const float* __restrict__ g,  const float* __restrict__ lb,
                             unsigned short* __restrict__ wg_bf, float* __restrict__ wgsum,
                             float* __restrict__ wbeta)
{
    int l = blockIdx.x;
    int e = threadIdx.x;            // 144 threads
    const float* wr = (l == 0) ? wr0 : ((l == 1) ? wr1 : wr2);
    const float* br = (l == 0) ? br0 : ((l == 1) ? br1 : br2);
    float sg = 0.f, sb = 0.f;
    for (int d = 0; d < DD; ++d) {
        float w = wr[e * DD + d];
        float wgv = w * g[d];
        wg_bf[((size_t)l * EE + e) * DD + d] = f2bf(wgv);
        sg += wgv;
        sb += w * lb[d];
    }
    wgsum[l * EE + e] = sg;
    wbeta[l * EE + e] = sb + br[e];
}

// ---------------- convert wqkv / we to bf16 with K padded 144->160 (zeros) ----------------
__global__ __launch_bounds__(256) void convw_k(
    const float* __restrict__ wqkv0, const float* __restrict__ wqkv1, const float* __restrict__ wqkv2,
    const float* __restrict__ we0,   const float* __restrict__ we1,   const float* __restrict__ we2,
    unsigned short* __restrict__ wqkv_bf, unsigned short* __restrict__ we_bf)
{
    int idx = blockIdx.x * 256 + threadIdx.x;
    const int T1 = 3 * 432 * 160;
    const int T2 = 3 * 288 * 160;
    if (idx < T1) {
        int l = idx / (432 * 160), r = idx % (432 * 160);
        int m = r / 160, k = r % 160;
        const float* w = (l == 0) ? wqkv0 : ((l == 1) ? wqkv1 : wqkv2);
        wqkv_bf[idx] = (k < 144) ? f2bf(w[m * 144 + k]) : 0;
    } else if (idx < T1 + T2) {
        int j = idx - T1;
        int l = j / (288 * 160), r = j % (288 * 160);
        int m = r / 160, k = r % 160;
        const float* w = (l == 0) ? we0 : ((l == 1) ? we1 : we2);
        we_bf[idx] = (k < 144) ? f2bf(w[m * 144 + k]) : 0;
    }
}

// ---------------- unfold + LN stats + bf16 token-major copy ----------------
// 256 blocks x 256 thr: block = (b, 64-token chunk); thread = (token, 8-channel part)
__global__ __launch_bounds__(256) void unfold_k(const float* __restrict__ t,
    float* __restrict__ cols_f, unsigned short* __restrict__ colsT,
    float* __restrict__ mu, float* __restrict__ rstd)
{
    __shared__ float red1[4][64], red2[4][64];
    int tid = threadIdx.x;
    int lane = tid & 63, cpart = tid >> 6;
    int b = blockIdx.x >> 6, nc = blockIdx.x & 63;
    int n = nc * 64 + lane;
    int h = n >> 6, w = n & 63;
    const float* tb = t + (size_t)b * CC * HH * WW;
    float* cf = cols_f + (size_t)b * DD * NTOK;
    unsigned short loc[72];
    float s1 = 0.f, s2 = 0.f;
    #pragma unroll
    for (int c8 = 0; c8 < 8; ++c8) {
        int c = cpart * 8 + c8;
        const float* tc = tb + (size_t)c * 4096;
        #pragma unroll
        for (int i = 0; i < 3; ++i) {
            int hr = h + i - 1;
            bool rok = ((unsigned)hr < 64u);
            #pragma unroll
            for (int j = 0; j < 3; ++j) {
                int wc = w + j - 1;
                bool ok = rok && ((unsigned)wc < 64u);
                float v = ok ? tc[hr * 64 + wc] : 0.f;
                cf[(size_t)(c * 9 + i * 3 + j) * NTOK + n] = v;
                loc[c8 * 9 + i * 3 + j] = f2bf(v);
                s1 += v;
                s2 = fmaf(v, v, s2);
            }
        }
    }
    unsigned short* ct = colsT + ((size_t)b * NTOK + n) * 288 + cpart * 72;
    #pragma unroll
    for (int u = 0; u < 9; ++u)
        *(u16x8*)&ct[u * 8] = *(const u16x8*)&loc[u * 8];
    red1[cpart][lane] = s1;
    red2[cpart][lane] = s2;
    __syncthreads();
    if (tid < 64) {
        float a = red1[0][tid] + red1[1][tid] + red1[2][tid] + red1[3][tid];
        float q = red2[0][tid] + red2[1][tid] + red2[2][tid] + red2[3][tid];
        float m = a * (1.f / 288.f);
        float var = q * (1.f / 288.f) - m * m;
        int nn = nc * 64 + tid;
        mu[b * NTOK + nn] = m;
        rstd[b * NTOK + nn] = rsqrtf(var + 1e-5f);
    }
}

// ---------------- bf16 MFMA GEMM: C[m][n] = sum_k A[m][k] * Bt[n][k] ----------------
// Tile 48x128, 4 waves (wave = 32 n-cols), mfma 16x16x32. A: [M][NCHUNK*BK] bf16.
// Bt: token-major [4096][BST] bf16. MODE 1: LN epilogue + transpose-store xrT[tok][160]
// (+zero pad at m0==96). MODE 0: m0<288 -> transpose-store qkT[tok][288]; else vF[144][4096].
// MODE 2: natural fp32 store with +bias +residual in-place (resid).
template<int BK, int NCHUNK, int MODE>
__global__ __launch_bounds__(256) void mgemm_k(
    const unsigned short* __restrict__ A, const unsigned short* __restrict__ Bt, int BST,
    unsigned short* __restrict__ Ct, unsigned short* __restrict__ Cv,
    const float* __restrict__ mu, const float* __restrict__ rstd,
    const float* __restrict__ wgsum, const float* __restrict__ wbeta,
    const float* __restrict__ bias, float* __restrict__ resid)
{
    constexpr int LDK = BK + 8;
    constexpr int AST = NCHUNK * BK;
    __shared__ unsigned short smem[176 * LDK];
    unsigned short* As = smem;
    unsigned short* Bs = smem + 48 * LDK;

    int n0 = blockIdx.x * 128;
    int m0 = blockIdx.y * 48;
    int bI = blockIdx.z;
    int tid = threadIdx.x;
    int wv = tid >> 6, lane = tid & 63;
    int l15 = lane & 15, l4 = lane >> 4;

    floatx4 acc[3][2];
    #pragma unroll
    for (int mi = 0; mi < 3; ++mi)
        #pragma unroll
        for (int ni = 0; ni < 2; ++ni)
            acc[mi][ni] = (floatx4){0.f, 0.f, 0.f, 0.f};

    const unsigned short* Bb = Bt + (size_t)bI * NTOK * BST;

    for (int c = 0; c < NCHUNK; ++c) {
        if (c) __syncthreads();
        int k0 = c * BK;
        // stage A: 48 rows x BK/8 chunks
        for (int u = tid; u < 48 * (BK / 8); u += 256) {
            int row = u / (BK / 8), seg = u % (BK / 8);
            *(u16x8*)&As[row * LDK + seg * 8] =
                *(const u16x8*)&A[(size_t)(m0 + row) * AST + k0 + seg * 8];
        }
        // stage B: 128 rows x BK/8 chunks
        for (int u = tid; u < 128 * (BK / 8); u += 256) {
            int row = u / (BK / 8), seg = u % (BK / 8);
            *(u16x8*)&Bs[row * LDK + seg * 8] =
                *(const u16x8*)&Bb[(size_t)(n0 + row) * BST + k0 + seg * 8];
        }
        __syncthreads();
        #pragma unroll
        for (int ks = 0; ks < BK / 32; ++ks) {
            bf16x8 af[3], bfr[2];
            #pragma unroll
            for (int mi = 0; mi < 3; ++mi)
                af[mi] = *(const bf16x8*)&As[(mi * 16 + l15) * LDK + ks * 32 + l4 * 8];
            #pragma unroll
            for (int ni = 0; ni < 2; ++ni)
                bfr[ni] = *(const bf16x8*)&Bs[(wv * 32 + ni * 16 + l15) * LDK + ks * 32 + l4 * 8];
            #pragma unroll
            for (int mi = 0; mi < 3; ++mi)
                #pragma unroll
                for (int ni = 0; ni < 2; ++ni)
                    acc[mi][ni] = __builtin_amdgcn_mfma_f32_16x16x32_bf16(af[mi], bfr[ni], acc[mi][ni], 0, 0, 0);
        }
    }

    if (MODE == 2) {
        #pragma unroll
        for (int mi = 0; mi < 3; ++mi)
            #pragma unroll
            for (int r = 0; r < 4; ++r) {
                int m_g = m0 + mi * 16 + l4 * 4 + r;
                float bb = bias[m_g];
                #pragma unroll
                for (int ni = 0; ni < 2; ++ni) {
                    int n_g = n0 + wv * 32 + ni * 16 + l15;
                    size_t ci = ((size_t)bI * DD + m_g) * NTOK + n_g;
                    resid[ci] += acc[mi][ni][r] + bb;
                }
            }
    } else {
        __syncthreads();
        unsigned short* Ts = smem;
        bool vpath = (MODE == 0) && (m0 >= 288);
        float muv[2], rsv[2];
        if (MODE == 1) {
            #pragma unroll
            for (int ni = 0; ni < 2; ++ni) {
                int n_g = n0 + wv * 32 + ni * 16 + l15;
                muv[ni] = mu[bI * NTOK + n_g];
                rsv[ni] = rstd[bI * NTOK + n_g];
            }
        }
        #pragma unroll
        for (int mi = 0; mi < 3; ++mi)
            #pragma unroll
            for (int r = 0; r < 4; ++r) {
                int m_l = mi * 16 + l4 * 4 + r;
                float wgs = 0.f, wbv = 0.f;
                if (MODE == 1) { wgs = wgsum[m0 + m_l]; wbv = wbeta[m0 + m_l]; }
                #pragma unroll
                for (int ni = 0; ni < 2; ++ni) {
                    int n_l = wv * 32 + ni * 16 + l15;
                    float v = acc[mi][ni][r];
                    if (MODE == 1) v = rsv[ni] * (v - muv[ni] * wgs) + wbv;
                    if (!vpath) Ts[n_l * 56 + m_l] = f2bf(v);
                    else        Ts[m_l * 136 + n_l] = f2bf(v);
                }
            }
        __syncthreads();
        if (!vpath) {
            const int CTS = (MODE == 1) ? 160 : 288;
            int row = tid >> 1, half = tid & 1;
            unsigned short* dst = Ct + ((size_t)bI * NTOK + n0 + row) * CTS + m0 + half * 24;
            const unsigned short* src = &Ts[row * 56 + half * 24];
            #pragma unroll
            for (int u = 0; u < 3; ++u)
                *(u16x8*)&dst[u * 8] = *(const u16x8*)&src[u * 8];
            if (MODE == 1 && m0 == 96) {
                u16x8 z = (u16x8)0;
                *(u16x8*)(Ct + ((size_t)bI * NTOK + n0 + row) * 160 + 144 + half * 8) = z;
            }
        } else {
            if (tid < 192) {
                int m = tid >> 2, seg = tid & 3;
                unsigned short* dst = Cv + ((size_t)bI * EE + (m0 - 288) + m) * NTOK + n0 + seg * 32;
                const unsigned short* src = &Ts[m * 136 + seg * 32];
                #pragma unroll
                for (int u = 0; u < 4; ++u)
                    *(u16x8*)&dst[u * 8] = *(const u16x8*)&src[u * 8];
            }
        }
    }
}

// ---------------- MFMA bf16 attention, bf16 IO ----------------
// qkT [b][tok][288] (Q at h*18, K at 144+h*18), vF [b][144][4096], oT [b][tok][160]
__global__ __launch_bounds__(256) void attn_k2(const unsigned short* __restrict__ qkT,
                                               const unsigned short* __restrict__ vF,
                                               unsigned short* __restrict__ oT)
{
    __shared__ unsigned short Qs[128 * 40];
    __shared__ unsigned short Ks[64 * 40];
    __shared__ unsigned short Vs[32 * 72];
    __shared__ unsigned short Ps[4 * 32 * 72];

    int blk = blockIdx.x;
    int qc  = blk & 7;
    int bhs = blk >> 3;
    int b = bhs >> 5, h = (bhs >> 2) & 7, s = bhs & 3;
    int tid  = threadIdx.x;
    int wv   = tid >> 6;
    int lane = tid & 63;
    int q0 = qc * 128;
    int tokbase = s * 1024;

    const unsigned short* qkb = qkT + (size_t)b * NTOK * 288;

    // ---- one-time: stage Q (scaled by SCALE*log2e) + pads ----
    if (tid < 128) {
        int q = tid;
        const unsigned short* src = qkb + (size_t)(tokbase + q0 + q) * 288 + h * 18;
        unsigned short* dq = &Qs[q * 40];
        #pragma unroll
        for (int i = 0; i < 9; ++i) {
            unsigned int u = *(const unsigned int*)&src[2 * i];
            float a  = __uint_as_float((u & 0xffffu) << 16) * QSCALE;
            float bb = __uint_as_float(u & 0xffff0000u) * QSCALE;
            *(unsigned int*)&dq[2 * i] = (unsigned)f2bf(a) | ((unsigned)f2bf(bb) << 16);
        }
        #pragma unroll
        for (int i = 0; i < 7; ++i) *(unsigned int*)&dq[18 + 2 * i] = 0;
    } else if (tid < 192) {
        int tok = tid - 128;                  // Ks pad cols 18..31
        #pragma unroll
        for (int i = 0; i < 7; ++i) *(unsigned int*)&Ks[tok * 40 + 18 + 2 * i] = 0;
    } else {
        for (int v = tid - 192; v < 112; v += 64) {   // Vs pad rows 18..31 (row31 = 1.0)
            int d = 18 + (v >> 3), seg = v & 7;
            unsigned short val = (d == 31) ? (unsigned short)0x3F80 : (unsigned short)0;
            u16x8 vv = (u16x8)val;
            *(u16x8*)&Vs[d * 72 + seg * 8] = vv;
        }
    }
    __syncthreads();

    int l15 = lane & 15, l4 = lane >> 4;
    bf16x8 qf[2];
    qf[0] = *(const bf16x8*)&Qs[(wv * 32 +      l15) * 40 + l4 * 8];
    qf[1] = *(const bf16x8*)&Qs[(wv * 32 + 16 + l15) * 40 + l4 * 8];

    floatx4 oacc[2][2];
    #pragma unroll
    for (int i = 0; i < 2; ++i)
        #pragma unroll
        for (int j = 0; j < 2; ++j)
            oacc[i][j] = (floatx4){0.f, 0.f, 0.f, 0.f};

    unsigned short* Pw = &Ps[wv * 32 * 72];

    for (int c0 = 0; c0 < 1024; c0 += 64) {
        __syncthreads();
        if (tid < 64) {                      // K rows (raw bf16 copy)
            int tok = tid;
            const unsigned short* src = qkb + (size_t)(tokbase + c0 + tok) * 288 + 144 + h * 18;
            unsigned short* dk = &Ks[tok * 40];
            #pragma unroll
            for (int i = 0; i < 9; ++i)
                *(unsigned int*)&dk[2 * i] = *(const unsigned int*)&src[2 * i];
        } else if (tid < 100) {              // V rows d<18, [d][tok]
            int u = tid - 64;
            int d = u >> 1, half = u & 1;
            const unsigned short* src = vF + ((size_t)b * EE + h * 18 + d) * NTOK + tokbase + c0 + half * 32;
            unsigned short* dv = &Vs[d * 72 + half * 32];
            #pragma unroll
            for (int i = 0; i < 4; ++i)
                *(u16x8*)&dv[i * 8] = *(const u16x8*)&src[i * 8];
        }
        __syncthreads();

        bf16x8 kf[4];
        #pragma unroll
        for (int mi = 0; mi < 4; ++mi)
            kf[mi] = *(const bf16x8*)&Ks[(mi * 16 + l15) * 40 + l4 * 8];

        floatx4 sacc[4][2];
        #pragma unroll
        for (int mi = 0; mi < 4; ++mi)
            #pragma unroll
            for (int ni = 0; ni < 2; ++ni) {
                floatx4 z = (floatx4){0.f, 0.f, 0.f, 0.f};
                sacc[mi][ni] = __builtin_amdgcn_mfma_f32_16x16x32_bf16(kf[mi], qf[ni], z, 0, 0, 0);
            }

        #pragma unroll
        for (int mi = 0; mi < 4; ++mi)
            #pragma unroll
            for (int ni = 0; ni < 2; ++ni) {
                int ql   = ni * 16 + l15;
                int tokb = mi * 16 + l4 * 4;
                ushort4 pk;
                pk.x = f2bf(exp2f(sacc[mi][ni][0]));
                pk.y = f2bf(exp2f(sacc[mi][ni][1]));
                pk.z = f2bf(exp2f(sacc[mi][ni][2]));
                pk.w = f2bf(exp2f(sacc[mi][ni][3]));
                *(ushort4*)&Pw[ql * 72 + tokb] = pk;
            }

        #pragma unroll
        for (int ks = 0; ks < 2; ++ks) {
            bf16x8 pf[2], vf[2];
            pf[0] = *(const bf16x8*)&Pw[(     l15) * 72 + ks * 32 + l4 * 8];
            pf[1] = *(const bf16x8*)&Pw[(16 + l15) * 72 + ks * 32 + l4 * 8];
            vf[0] = *(const bf16x8*)&Vs[(     l15) * 72 + ks * 32 + l4 * 8];
            vf[1] = *(const bf16x8*)&Vs[(16 + l15) * 72 + ks * 32 + l4 * 8];
            #pragma unroll
            for (int mi = 0; mi < 2; ++mi)
                #pragma unroll
                for (int nd = 0; nd < 2; ++nd)
                    oacc[mi][nd] = __builtin_amdgcn_mfma_f32_16x16x32_bf16(pf[mi], vf[nd], oacc[mi][nd], 0, 0, 0);
        }
    }

    // normalize by l (O col 31) -> fO [q][33] fp32 in dead P region
    float* fO = (float*)Pw;
    #pragma unroll
    for (int mi = 0; mi < 2; ++mi)
        #pragma unroll
        for (int r = 0; r < 4; ++r) {
            float lsum = __shfl(oacc[mi][1][r], (lane & 48) | 15, 64);
            float inv  = 1.f / lsum;
            int ql = mi * 16 + l4 * 4 + r;
            fO[ql * 33 + l15] = oacc[mi][0][r] * inv;
            if (l15 < 2) fO[ql * 33 + 16 + l15] = oacc[mi][1][r] * inv;
        }

    {
        int q = lane & 31, dh = lane >> 5;
        size_t rowi = (size_t)b * NTOK + tokbase + q0 + wv * 32 + q;
        unsigned short* orow = oT + rowi * 160 + h * 18;
        for (int i = dh; i < 9; i += 2) {
            float a  = fO[q * 33 + 2 * i];
            float bb = fO[q * 33 + 2 * i + 1];
            *(unsigned int*)&orow[2 * i] = (unsigned)f2bf(a) | ((unsigned)f2bf(bb) << 16);
        }
        if (h == 7) {
            u16x8 z = (u16x8)0;
            *(u16x8*)(oT + rowi * 160 + 144 + dh * 8) = z;
        }
    }
}

// ---------------- fold (scatter-add of 3x3 patches, crop) ----------------
__global__ __launch_bounds__(256) void fold_k(const float* __restrict__ cols, float* __restrict__ t)
{
    int idx = blockIdx.x * 256 + threadIdx.x;
    int w = idx & 63;
    int h = (idx >> 6) & 63;
    int c = (idx >> 12) & 31;
    int b = idx >> 17;
    const float* cb = cols + (size_t)b * DD * NTOK + (size_t)c * 9 * NTOK;
    float sum = 0.f;
    #pragma unroll
    for (int i = 0; i < 3; ++i) {
        int hs = h + 1 - i;
        if ((unsigned)hs < 64u) {
            #pragma unroll
            for (int j = 0; j < 3; ++j) {
                int ws_ = w + 1 - j;
                if ((unsigned)ws_ < 64u)
                    sum += cb[(size_t)(i * 3 + j) * NTOK + hs * 64 + ws_];
            }
        }
    }
    t[idx] = sum;
}

// ---------------- conv3x3 + ELU + residual ----------------
__global__ __launch_bounds__(256) void conv_k(const float* __restrict__ t,
    const float* __restrict__ cw, const float* __restrict__ cbias,
    const float* __restrict__ x, float* __restrict__ out)
{
    __shared__ float wsh[CC * 9];
    int idx = blockIdx.x * 256 + threadIdx.x;
    int w = idx & 63;
    int h = (idx >> 6) & 63;
    int co = (idx >> 12) & 31;
    int b = idx >> 17;
    int tid = threadIdx.x;
    for (int u = tid; u < CC * 9; u += 256) wsh[u] = cw[co * CC * 9 + u];
    __syncthreads();
    const float* tb = t + (size_t)b * CC * HH * WW;
    float acc = cbias[co];
    for (int ci = 0; ci < CC; ++ci) {
        const float* tc = tb + (size_t)ci * HH * WW;
        const float* wrow = &wsh[ci * 9];
        #pragma unroll
        for (int i = 0; i < 3; ++i) {
            int hr = h + i - 1;
            if ((unsigned)hr < 64u) {
                #pragma unroll
                for (int j = 0; j < 3; ++j) {
                    int wc = w + j - 1;
                    if ((unsigned)wc < 64u)
                        acc = fmaf(wrow[i * 3 + j], tc[hr * 64 + wc], acc);
                }
            }
        }
    }
    float e = (acc > 0.f) ? acc : (__expf(acc) - 1.f);
    out[idx] = x[idx] + e;
}

extern "C" void kernel_launch(void* const* d_in, const int* in_sizes, int n_in,
                              void* d_out, int out_size, void* d_ws, size_t ws_size,
                              hipStream_t stream)
{
    const float* x    = (const float*)d_in[0];
    const float* ln_g = (const float*)d_in[1];
    const float* ln_b = (const float*)d_in[2];
    const float* cw   = (const float*)d_in[3];
    const float* cb   = (const float*)d_in[4];
    const float* wr[3]   = {(const float*)d_in[5],  (const float*)d_in[10], (const float*)d_in[15]};
    const float* br[3]   = {(const float*)d_in[6],  (const float*)d_in[11], (const float*)d_in[16]};
    const float* wqkv[3] = {(const float*)d_in[7],  (const float*)d_in[12], (const float*)d_in[17]};
    const float* we[3]   = {(const float*)d_in[8],  (const float*)d_in[13], (const float*)d_in[18]};
    const float* be[3]   = {(const float*)d_in[9],  (const float*)d_in[14], (const float*)d_in[19]};
    float* out = (float*)d_out;

    char* p = (char*)d_ws;
    float* cols_f = (float*)p;            p += (size_t)BN * DD * NTOK * 4;        // 18.9 MB
    unsigned short* colsT = (unsigned short*)p; p += (size_t)BN * NTOK * 288 * 2; // 9.4 MB
    unsigned short* xrT   = (unsigned short*)p; p += (size_t)BN * NTOK * 160 * 2; // 5.2 MB
    unsigned short* qkT   = (unsigned short*)p; p += (size_t)BN * NTOK * 288 * 2; // 9.4 MB
    unsigned short* vF    = (unsigned short*)p; p += (size_t)BN * EE * NTOK * 2;  // 4.7 MB
    unsigned short* oT    = (unsigned short*)p; p += (size_t)BN * NTOK * 160 * 2; // 5.2 MB
    float* mu   = (float*)p;              p += (size_t)BN * NTOK * 4;
    float* rstd = (float*)p;              p += (size_t)BN * NTOK * 4;
    float* tA   = (float*)p;              p += (size_t)BN * CC * HH * WW * 4;
    float* tB   = (float*)p;              p += (size_t)BN * CC * HH * WW * 4;
    unsigned short* wg_bf   = (unsigned short*)p; p += (size_t)3 * EE * DD * 2;
    unsigned short* wqkv_bf = (unsigned short*)p; p += (size_t)3 * 432 * 160 * 2;
    unsigned short* we_bf   = (unsigned short*)p; p += (size_t)3 * DD * 160 * 2;
    float* wgsum = (float*)p;             p += 3 * EE * 4;
    float* wbeta = (float*)p;             p += 3 * EE * 4;
    (void)in_sizes; (void)n_in; (void)out_size; (void)ws_size;

    precompute_k<<<3, 144, 0, stream>>>(wr[0], br[0], wr[1], br[1], wr[2], br[2],
                                        ln_g, ln_b, wg_bf, wgsum, wbeta);
    convw_k<<<1350, 256, 0, stream>>>(wqkv[0], wqkv[1], wqkv[2], we[0], we[1], we[2],
                                      wqkv_bf, we_bf);

    const float* tin = x;
    float* touts[3] = {tA, tB, tA};
    for (int l = 0; l < 3; ++l) {
        unfold_k<<<256, 256, 0, stream>>>(tin, cols_f, colsT, mu, rstd);
        mgemm_k<96, 3, 1><<<dim3(32, 3, 4), 256, 0, stream>>>(
            wg_bf + (size_t)l * EE * DD, colsT, 288, xrT, nullptr,
            mu, rstd, wgsum + l * EE, wbeta + l * EE, nullptr, nullptr);
        mgemm_k<160, 1, 0><<<dim3(32, 9, 4), 256, 0, stream>>>(
            wqkv_bf + (size_t)l * 432 * 160, xrT, 160, qkT, vF,
            nullptr, nullptr, nullptr, nullptr, nullptr, nullptr);
        attn_k2<<<1024, 256, 0, stream>>>(qkT, vF, oT);
        mgemm_k<160, 1, 2><<<dim3(32, 6, 4), 256, 0, stream>>>(
            we_bf + (size_t)l * DD * 160, oT, 160, nullptr, nullptr,
            nullptr, nullptr, nullptr, nullptr, be[l], cols_f);
        fold_k<<<2048, 256, 0, stream>>>(cols_f, touts[l]);
        tin = touts[l];
    }
    conv_k<<<2048, 256, 0, stream>>>(tA, cw, cb, x, out);
}

// Round 5
// 528.461 us; speedup vs baseline: 3.0035x; 1.0154x over previous
//
#include <hip/hip_runtime.h>
#include <math.h>

#define BN 4
#define CC 32
#define HH 64
#define WW 64
#define DD 288          // C*K*K
#define EE 144
#define NTOK 4096
#define SCALE_F 0.2357022603955158f           // 18^-0.5
#define QSCALE  0.3401074286f                 // SCALE_F * log2(e)

typedef __bf16 bf16x8 __attribute__((ext_vector_type(8)));
typedef float floatx4 __attribute__((ext_vector_type(4)));
typedef unsigned short u16x8 __attribute__((ext_vector_type(8)));

__device__ __forceinline__ unsigned short f2bf(float x) {
    unsigned int u = __float_as_uint(x);
    u += 0x7fffu + ((u >> 16) & 1u);          // RNE
    return (unsigned short)(u >> 16);
}
// pack hi16(a), hi16(b) -> (b_hi<<16)|a_hi  — single v_perm_b32
__device__ __forceinline__ unsigned int pack_bf_trunc(float a, float b) {
    return __builtin_amdgcn_perm(__float_as_uint(b), __float_as_uint(a), 0x07060302u);
}

// ---------------- precompute LN-folded reduction weights (bf16) ----------------
__global__ void precompute_k(const float* __restrict__ wr0, const float* __restrict__ br0,
                             const float* __restrict__ wr1, const float* __restrict__ br1,
                             const float* __restrict__ wr2, const float* __restrict__ br2,
                             const float* __restrict__ g,  const float* __restrict__ lb,
                             unsigned short* __restrict__ wg_bf, float* __restrict__ wgsum,
                             float* __restrict__ wbeta)
{
    int l = blockIdx.x;
    int e = threadIdx.x;            // 144 threads
    const float* wr = (l == 0) ? wr0 : ((l == 1) ? wr1 : wr2);
    const float* br = (l == 0) ? br0 : ((l == 1) ? br1 : br2);
    float sg = 0.f, sb = 0.f;
    for (int d = 0; d < DD; ++d) {
        float w = wr[e * DD + d];
        float wgv = w * g[d];
        wg_bf[((size_t)l * EE + e) * DD + d] = f2bf(wgv);
        sg += wgv;
        sb += w * lb[d];
    }
    wgsum[l * EE + e] = sg;
    wbeta[l * EE + e] = sb + br[e];
}

// ---------------- convert wqkv / we to bf16 with K padded 144->160 (zeros) ----------------
__global__ __launch_bounds__(256) void convw_k(
    const float* __restrict__ wqkv0, const float* __restrict__ wqkv1, const float* __restrict__ wqkv2,
    const float* __restrict__ we0,   const float* __restrict__ we1,   const float* __restrict__ we2,
    unsigned short* __restrict__ wqkv_bf, unsigned short* __restrict__ we_bf)
{
    int idx = blockIdx.x * 256 + threadIdx.x;
    const int T1 = 3 * 432 * 160;
    const int T2 = 3 * 288 * 160;
    if (idx < T1) {
        int l = idx / (432 * 160), r = idx % (432 * 160);
        int m = r / 160, k = r % 160;
        const float* w = (l == 0) ? wqkv0 : ((l == 1) ? wqkv1 : wqkv2);
        wqkv_bf[idx] = (k < 144) ? f2bf(w[m * 144 + k]) : 0;
    } else if (idx < T1 + T2) {
        int j = idx - T1;
        int l = j / (288 * 160), r = j % (288 * 160);
        int m = r / 160, k = r % 160;
        const float* w = (l == 0) ? we0 : ((l == 1) ? we1 : we2);
        we_bf[idx] = (k < 144) ? f2bf(w[m * 144 + k]) : 0;
    }
}

// ---------------- unfold + LN stats + bf16 token-major copy ----------------
__global__ __launch_bounds__(256) void unfold_k(const float* __restrict__ t,
    float* __restrict__ cols_f, unsigned short* __restrict__ colsT,
    float* __restrict__ mu, float* __restrict__ rstd)
{
    __shared__ float red1[4][64], red2[4][64];
    int tid = threadIdx.x;
    int lane = tid & 63, cpart = tid >> 6;
    int b = blockIdx.x >> 6, nc = blockIdx.x & 63;
    int n = nc * 64 + lane;
    int h = n >> 6, w = n & 63;
    const float* tb = t + (size_t)b * CC * HH * WW;
    float* cf = cols_f + (size_t)b * DD * NTOK;
    unsigned short loc[72];
    float s1 = 0.f, s2 = 0.f;
    #pragma unroll
    for (int c8 = 0; c8 < 8; ++c8) {
        int c = cpart * 8 + c8;
        const float* tc = tb + (size_t)c * 4096;
        #pragma unroll
        for (int i = 0; i < 3; ++i) {
            int hr = h + i - 1;
            bool rok = ((unsigned)hr < 64u);
            #pragma unroll
            for (int j = 0; j < 3; ++j) {
                int wc = w + j - 1;
                bool ok = rok && ((unsigned)wc < 64u);
                float v = ok ? tc[hr * 64 + wc] : 0.f;
                cf[(size_t)(c * 9 + i * 3 + j) * NTOK + n] = v;
                loc[c8 * 9 + i * 3 + j] = f2bf(v);
                s1 += v;
                s2 = fmaf(v, v, s2);
            }
        }
    }
    unsigned short* ct = colsT + ((size_t)b * NTOK + n) * 288 + cpart * 72;
    #pragma unroll
    for (int u = 0; u < 9; ++u)
        *(u16x8*)&ct[u * 8] = *(const u16x8*)&loc[u * 8];
    red1[cpart][lane] = s1;
    red2[cpart][lane] = s2;
    __syncthreads();
    if (tid < 64) {
        float a = red1[0][tid] + red1[1][tid] + red1[2][tid] + red1[3][tid];
        float q = red2[0][tid] + red2[1][tid] + red2[2][tid] + red2[3][tid];
        float m = a * (1.f / 288.f);
        float var = q * (1.f / 288.f) - m * m;
        int nn = nc * 64 + tid;
        mu[b * NTOK + nn] = m;
        rstd[b * NTOK + nn] = rsqrtf(var + 1e-5f);
    }
}

// ---------------- bf16 MFMA GEMM: C[m][n] = sum_k A[m][k] * Bt[n][k] ----------------
// Tile 48xNT, 4 waves (wave = NT/4 n-cols), mfma 16x16x32.
// MODE 1: LN epilogue + transpose-store xrT[tok][160] (+pad at m0==96).
// MODE 0: m0<288 -> transpose-store qkT[tok][288]; else vF[144][4096] (NT=128 only).
// MODE 2: natural fp32 store +bias +residual in-place.
template<int BK, int NCHUNK, int MODE, int NT>
__global__ __launch_bounds__(256) void mgemm_k(
    const unsigned short* __restrict__ A, const unsigned short* __restrict__ Bt, int BST,
    unsigned short* __restrict__ Ct, unsigned short* __restrict__ Cv,
    const float* __restrict__ mu, const float* __restrict__ rstd,
    const float* __restrict__ wgsum, const float* __restrict__ wbeta,
    const float* __restrict__ bias, float* __restrict__ resid)
{
    constexpr int LDK = BK + 8;
    constexpr int AST = NCHUNK * BK;
    constexpr int NI  = NT / 64;
    __shared__ unsigned short smem[(48 + NT) * LDK];
    unsigned short* As = smem;
    unsigned short* Bs = smem + 48 * LDK;

    int n0 = blockIdx.x * NT;
    int m0 = blockIdx.y * 48;
    int bI = blockIdx.z;
    int tid = threadIdx.x;
    int wv = tid >> 6, lane = tid & 63;
    int l15 = lane & 15, l4 = lane >> 4;

    floatx4 acc[3][NI];
    #pragma unroll
    for (int mi = 0; mi < 3; ++mi)
        #pragma unroll
        for (int ni = 0; ni < NI; ++ni)
            acc[mi][ni] = (floatx4){0.f, 0.f, 0.f, 0.f};

    const unsigned short* Bb = Bt + (size_t)bI * NTOK * BST;

    for (int c = 0; c < NCHUNK; ++c) {
        if (c) __syncthreads();
        int k0 = c * BK;
        for (int u = tid; u < 48 * (BK / 8); u += 256) {
            int row = u / (BK / 8), seg = u % (BK / 8);
            *(u16x8*)&As[row * LDK + seg * 8] =
                *(const u16x8*)&A[(size_t)(m0 + row) * AST + k0 + seg * 8];
        }
        for (int u = tid; u < NT * (BK / 8); u += 256) {
            int row = u / (BK / 8), seg = u % (BK / 8);
            *(u16x8*)&Bs[row * LDK + seg * 8] =
                *(const u16x8*)&Bb[(size_t)(n0 + row) * BST + k0 + seg * 8];
        }
        __syncthreads();
        #pragma unroll
        for (int ks = 0; ks < BK / 32; ++ks) {
            bf16x8 af[3], bfr[NI];
            #pragma unroll
            for (int mi = 0; mi < 3; ++mi)
                af[mi] = *(const bf16x8*)&As[(mi * 16 + l15) * LDK + ks * 32 + l4 * 8];
            #pragma unroll
            for (int ni = 0; ni < NI; ++ni)
                bfr[ni] = *(const bf16x8*)&Bs[(wv * (NT / 4) + ni * 16 + l15) * LDK + ks * 32 + l4 * 8];
            #pragma unroll
            for (int mi = 0; mi < 3; ++mi)
                #pragma unroll
                for (int ni = 0; ni < NI; ++ni)
                    acc[mi][ni] = __builtin_amdgcn_mfma_f32_16x16x32_bf16(af[mi], bfr[ni], acc[mi][ni], 0, 0, 0);
        }
    }

    if (MODE == 2) {
        #pragma unroll
        for (int mi = 0; mi < 3; ++mi)
            #pragma unroll
            for (int r = 0; r < 4; ++r) {
                int m_g = m0 + mi * 16 + l4 * 4 + r;
                float bb = bias[m_g];
                #pragma unroll
                for (int ni = 0; ni < NI; ++ni) {
                    int n_g = n0 + wv * (NT / 4) + ni * 16 + l15;
                    size_t ci = ((size_t)bI * DD + m_g) * NTOK + n_g;
                    resid[ci] += acc[mi][ni][r] + bb;
                }
            }
    } else {
        __syncthreads();
        unsigned short* Ts = smem;
        bool vpath = (MODE == 0) && (m0 >= 288);
        float muv[NI], rsv[NI];
        if (MODE == 1) {
            #pragma unroll
            for (int ni = 0; ni < NI; ++ni) {
                int n_g = n0 + wv * (NT / 4) + ni * 16 + l15;
                muv[ni] = mu[bI * NTOK + n_g];
                rsv[ni] = rstd[bI * NTOK + n_g];
            }
        }
        #pragma unroll
        for (int mi = 0; mi < 3; ++mi)
            #pragma unroll
            for (int r = 0; r < 4; ++r) {
                int m_l = mi * 16 + l4 * 4 + r;
                float wgs = 0.f, wbv = 0.f;
                if (MODE == 1) { wgs = wgsum[m0 + m_l]; wbv = wbeta[m0 + m_l]; }
                #pragma unroll
                for (int ni = 0; ni < NI; ++ni) {
                    int n_l = wv * (NT / 4) + ni * 16 + l15;
                    float v = acc[mi][ni][r];
                    if (MODE == 1) v = rsv[ni] * (v - muv[ni] * wgs) + wbv;
                    if (!vpath) Ts[n_l * 56 + m_l] = f2bf(v);
                    else        Ts[m_l * 136 + n_l] = f2bf(v);
                }
            }
        __syncthreads();
        if (!vpath) {
            const int CTS = (MODE == 1) ? 160 : 288;
            for (int rr = tid; rr < NT * 2; rr += 256) {
                int row = rr >> 1, half = rr & 1;
                unsigned short* dst = Ct + ((size_t)bI * NTOK + n0 + row) * CTS + m0 + half * 24;
                const unsigned short* src = &Ts[row * 56 + half * 24];
                #pragma unroll
                for (int u = 0; u < 3; ++u)
                    *(u16x8*)&dst[u * 8] = *(const u16x8*)&src[u * 8];
                if (MODE == 1 && m0 == 96) {
                    u16x8 z = (u16x8)0;
                    *(u16x8*)(Ct + ((size_t)bI * NTOK + n0 + row) * 160 + 144 + half * 8) = z;
                }
            }
        } else {
            if (tid < 192) {
                int m = tid >> 2, seg = tid & 3;
                unsigned short* dst = Cv + ((size_t)bI * EE + (m0 - 288) + m) * NTOK + n0 + seg * 32;
                const unsigned short* src = &Ts[m * 136 + seg * 32];
                #pragma unroll
                for (int u = 0; u < 4; ++u)
                    *(u16x8*)&dst[u * 8] = *(const u16x8*)&src[u * 8];
            }
        }
    }
}

// ---------------- MFMA bf16 attention, 128-key chunks, XCD-swizzled grid ----------------
// qkT [b][tok][288] (Q at h*18, K at 144+h*18), vF [b][144][4096], oT [b][tok][160]
// blk = qc*128 + bhs  (qc slow -> all 8 q-chunks of a bhs land on the same XCD)
__global__ __launch_bounds__(256) void attn_k2(const unsigned short* __restrict__ qkT,
                                               const unsigned short* __restrict__ vF,
                                               unsigned short* __restrict__ oT)
{
    __shared__ unsigned short Qs[128 * 40];       // [q][d pad 40]
    __shared__ unsigned short Ks[128 * 40];       // [tok][d pad 40]
    __shared__ unsigned short Vs[32 * 136];       // [d][tok pad 136]
    __shared__ unsigned short Ps[4 * 32 * 72];    // per-wave [q][tok(64) pad 72]

    int blk = blockIdx.x;
    int bhs = blk & 127;
    int qc  = blk >> 7;
    int b = bhs >> 5, h = (bhs >> 2) & 7, s = bhs & 3;
    int tid  = threadIdx.x;
    int wv   = tid >> 6;
    int lane = tid & 63;
    int q0 = qc * 128;
    int tokbase = s * 1024;

    const unsigned short* qkb = qkT + (size_t)b * NTOK * 288;

    // ---- init: Q staging (scaled), Ks pad cols, Vs pad rows ----
    if (tid < 128) {
        int q = tid;
        const unsigned short* src = qkb + (size_t)(tokbase + q0 + q) * 288 + h * 18;
        unsigned short* dq = &Qs[q * 40];
        #pragma unroll
        for (int i = 0; i < 9; ++i) {
            unsigned int u = *(const unsigned int*)&src[2 * i];
            float a  = __uint_as_float((u & 0xffffu) << 16) * QSCALE;
            float bb = __uint_as_float(u & 0xffff0000u) * QSCALE;
            *(unsigned int*)&dq[2 * i] = pack_bf_trunc(a, bb);
        }
        #pragma unroll
        for (int i = 0; i < 7; ++i) *(unsigned int*)&dq[18 + 2 * i] = 0;
    } else {
        int u = tid - 128;
        {   // Ks pad cols 18..31 for row u
            unsigned short* dk = &Ks[u * 40];
            #pragma unroll
            for (int i = 0; i < 7; ++i) *(unsigned int*)&dk[18 + 2 * i] = 0;
        }
        for (int v = u; v < 14 * 17; v += 128) {      // Vs rows 18..31, 17 segs of 8
            int d = 18 + v / 17, seg = v % 17;
            unsigned short val = (d == 31) ? (unsigned short)0x3F80 : (unsigned short)0;
            u16x8 vv = (u16x8)val;
            *(u16x8*)&Vs[d * 136 + seg * 8] = vv;
        }
    }

    int l15 = lane & 15, l4 = lane >> 4;

    floatx4 oacc[2][2];
    #pragma unroll
    for (int i = 0; i < 2; ++i)
        #pragma unroll
        for (int j = 0; j < 2; ++j)
            oacc[i][j] = (floatx4){0.f, 0.f, 0.f, 0.f};

    unsigned short* Pw = &Ps[wv * 32 * 72];
    bf16x8 qf[2];

    for (int c0 = 0; c0 < 1024; c0 += 128) {
        __syncthreads();                     // LDS safe (prev readers done / init done)
        if (tid < 128) {                     // K rows: raw bf16 copy, 9 dwords
            int tok = tid;
            const unsigned short* src = qkb + (size_t)(tokbase + c0 + tok) * 288 + 144 + h * 18;
            unsigned short* dk = &Ks[tok * 40];
            #pragma unroll
            for (int i = 0; i < 9; ++i)
                *(unsigned int*)&dk[2 * i] = *(const unsigned int*)&src[2 * i];
        } else {                             // V rows d<18: 18 x 16 segs of 8 toks
            for (int idx = tid - 128; idx < 18 * 16; idx += 128) {
                int d = idx >> 4, seg = idx & 15;
                const unsigned short* src = vF + ((size_t)b * EE + h * 18 + d) * NTOK + tokbase + c0 + seg * 8;
                *(u16x8*)&Vs[d * 136 + seg * 8] = *(const u16x8*)src;
            }
        }
        __syncthreads();
        if (c0 == 0) {
            qf[0] = *(const bf16x8*)&Qs[(wv * 32 +      l15) * 40 + l4 * 8];
            qf[1] = *(const bf16x8*)&Qs[(wv * 32 + 16 + l15) * 40 + l4 * 8];
        }

        #pragma unroll
        for (int sub = 0; sub < 2; ++sub) {
            // S^T: m = token (4 tiles of 16), n = q (2 tiles)
            bf16x8 kf[4];
            #pragma unroll
            for (int mi = 0; mi < 4; ++mi)
                kf[mi] = *(const bf16x8*)&Ks[(sub * 64 + mi * 16 + l15) * 40 + l4 * 8];

            floatx4 sacc[4][2];
            #pragma unroll
            for (int mi = 0; mi < 4; ++mi)
                #pragma unroll
                for (int ni = 0; ni < 2; ++ni) {
                    floatx4 z = (floatx4){0.f, 0.f, 0.f, 0.f};
                    sacc[mi][ni] = __builtin_amdgcn_mfma_f32_16x16x32_bf16(kf[mi], qf[ni], z, 0, 0, 0);
                }

            // exp2 + truncation-pack (v_perm) -> wave-private P [q][tok64]
            #pragma unroll
            for (int mi = 0; mi < 4; ++mi)
                #pragma unroll
                for (int ni = 0; ni < 2; ++ni) {
                    int ql   = ni * 16 + l15;
                    int tokb = mi * 16 + l4 * 4;
                    unsigned int lo = pack_bf_trunc(exp2f(sacc[mi][ni][0]), exp2f(sacc[mi][ni][1]));
                    unsigned int hi = pack_bf_trunc(exp2f(sacc[mi][ni][2]), exp2f(sacc[mi][ni][3]));
                    uint2 pk = make_uint2(lo, hi);
                    *(uint2*)&Pw[ql * 72 + tokb] = pk;
                }

            // PV: m = q (2), n = d (2), k = token (2 steps of 32)
            #pragma unroll
            for (int ks = 0; ks < 2; ++ks) {
                bf16x8 pf[2], vf[2];
                pf[0] = *(const bf16x8*)&Pw[(     l15) * 72 + ks * 32 + l4 * 8];
                pf[1] = *(const bf16x8*)&Pw[(16 + l15) * 72 + ks * 32 + l4 * 8];
                vf[0] = *(const bf16x8*)&Vs[(     l15) * 136 + sub * 64 + ks * 32 + l4 * 8];
                vf[1] = *(const bf16x8*)&Vs[(16 + l15) * 136 + sub * 64 + ks * 32 + l4 * 8];
                #pragma unroll
                for (int mi = 0; mi < 2; ++mi)
                    #pragma unroll
                    for (int nd = 0; nd < 2; ++nd)
                        oacc[mi][nd] = __builtin_amdgcn_mfma_f32_16x16x32_bf16(pf[mi], vf[nd], oacc[mi][nd], 0, 0, 0);
            }
        }
    }

    // normalize by l (O col 31) -> fO [q][33] fp32 in dead P region (wave-private)
    float* fO = (float*)Pw;
    #pragma unroll
    for (int mi = 0; mi < 2; ++mi)
        #pragma unroll
        for (int r = 0; r < 4; ++r) {
            float lsum = __shfl(oacc[mi][1][r], (lane & 48) | 15, 64);
            float inv  = 1.f / lsum;
            int ql = mi * 16 + l4 * 4 + r;
            fO[ql * 33 + l15] = oacc[mi][0][r] * inv;
            if (l15 < 2) fO[ql * 33 + 16 + l15] = oacc[mi][1][r] * inv;
        }

    {
        int q = lane & 31, dh = lane >> 5;
        size_t rowi = (size_t)b * NTOK + tokbase + q0 + wv * 32 + q;
        unsigned short* orow = oT + rowi * 160 + h * 18;
        for (int i = dh; i < 9; i += 2) {
            float a  = fO[q * 33 + 2 * i];
            float bb = fO[q * 33 + 2 * i + 1];
            *(unsigned int*)&orow[2 * i] = (unsigned)f2bf(a) | ((unsigned)f2bf(bb) << 16);
        }
        if (h == 7) {
            u16x8 z = (u16x8)0;
            *(u16x8*)(oT + rowi * 160 + 144 + dh * 8) = z;
        }
    }
}

// ---------------- fold (scatter-add of 3x3 patches, crop) ----------------
__global__ __launch_bounds__(256) void fold_k(const float* __restrict__ cols, float* __restrict__ t)
{
    int idx = blockIdx.x * 256 + threadIdx.x;
    int w = idx & 63;
    int h = (idx >> 6) & 63;
    int c = (idx >> 12) & 31;
    int b = idx >> 17;
    const float* cb = cols + (size_t)b * DD * NTOK + (size_t)c * 9 * NTOK;
    float sum = 0.f;
    #pragma unroll
    for (int i = 0; i < 3; ++i) {
        int hs = h + 1 - i;
        if ((unsigned)hs < 64u) {
            #pragma unroll
            for (int j = 0; j < 3; ++j) {
                int ws_ = w + 1 - j;
                if ((unsigned)ws_ < 64u)
                    sum += cb[(size_t)(i * 3 + j) * NTOK + hs * 64 + ws_];
            }
        }
    }
    t[idx] = sum;
}

// ---------------- conv3x3 + ELU + residual ----------------
__global__ __launch_bounds__(256) void conv_k(const float* __restrict__ t,
    const float* __restrict__ cw, const float* __restrict__ cbias,
    const float* __restrict__ x, float* __restrict__ out)
{
    __shared__ float wsh[CC * 9];
    int idx = blockIdx.x * 256 + threadIdx.x;
    int w = idx & 63;
    int h = (idx >> 6) & 63;
    int co = (idx >> 12) & 31;
    int b = idx >> 17;
    int tid = threadIdx.x;
    for (int u = tid; u < CC * 9; u += 256) wsh[u] = cw[co * CC * 9 + u];
    __syncthreads();
    const float* tb = t + (size_t)b * CC * HH * WW;
    float acc = cbias[co];
    for (int ci = 0; ci < CC; ++ci) {
        const float* tc = tb + (size_t)ci * HH * WW;
        const float* wrow = &wsh[ci * 9];
        #pragma unroll
        for (int i = 0; i < 3; ++i) {
            int hr = h + i - 1;
            if ((unsigned)hr < 64u) {
                #pragma unroll
                for (int j = 0; j < 3; ++j) {
                    int wc = w + j - 1;
                    if ((unsigned)wc < 64u)
                        acc = fmaf(wrow[i * 3 + j], tc[hr * 64 + wc], acc);
                }
            }
        }
    }
    float e = (acc > 0.f) ? acc : (__expf(acc) - 1.f);
    out[idx] = x[idx] + e;
}

extern "C" void kernel_launch(void* const* d_in, const int* in_sizes, int n_in,
                              void* d_out, int out_size, void* d_ws, size_t ws_size,
                              hipStream_t stream)
{
    const float* x    = (const float*)d_in[0];
    const float* ln_g = (const float*)d_in[1];
    const float* ln_b = (const float*)d_in[2];
    const float* cw   = (const float*)d_in[3];
    const float* cb   = (const float*)d_in[4];
    const float* wr[3]   = {(const float*)d_in[5],  (const float*)d_in[10], (const float*)d_in[15]};
    const float* br[3]   = {(const float*)d_in[6],  (const float*)d_in[11], (const float*)d_in[16]};
    const float* wqkv[3] = {(const float*)d_in[7],  (const float*)d_in[12], (const float*)d_in[17]};
    const float* we[3]   = {(const float*)d_in[8],  (const float*)d_in[13], (const float*)d_in[18]};
    const float* be[3]   = {(const float*)d_in[9],  (const float*)d_in[14], (const float*)d_in[19]};
    float* out = (float*)d_out;

    char* p = (char*)d_ws;
    float* cols_f = (float*)p;            p += (size_t)BN * DD * NTOK * 4;
    unsigned short* colsT = (unsigned short*)p; p += (size_t)BN * NTOK * 288 * 2;
    unsigned short* xrT   = (unsigned short*)p; p += (size_t)BN * NTOK * 160 * 2;
    unsigned short* qkT   = (unsigned short*)p; p += (size_t)BN * NTOK * 288 * 2;
    unsigned short* vF    = (unsigned short*)p; p += (size_t)BN * EE * NTOK * 2;
    unsigned short* oT    = (unsigned short*)p; p += (size_t)BN * NTOK * 160 * 2;
    float* mu   = (float*)p;              p += (size_t)BN * NTOK * 4;
    float* rstd = (float*)p;              p += (size_t)BN * NTOK * 4;
    float* tA   = (float*)p;              p += (size_t)BN * CC * HH * WW * 4;
    float* tB   = (float*)p;              p += (size_t)BN * CC * HH * WW * 4;
    unsigned short* wg_bf   = (unsigned short*)p; p += (size_t)3 * EE * DD * 2;
    unsigned short* wqkv_bf = (unsigned short*)p; p += (size_t)3 * 432 * 160 * 2;
    unsigned short* we_bf   = (unsigned short*)p; p += (size_t)3 * DD * 160 * 2;
    float* wgsum = (float*)p;             p += 3 * EE * 4;
    float* wbeta = (float*)p;             p += 3 * EE * 4;
    (void)in_sizes; (void)n_in; (void)out_size; (void)ws_size;

    precompute_k<<<3, 144, 0, stream>>>(wr[0], br[0], wr[1], br[1], wr[2], br[2],
                                        ln_g, ln_b, wg_bf, wgsum, wbeta);
    convw_k<<<1350, 256, 0, stream>>>(wqkv[0], wqkv[1], wqkv[2], we[0], we[1], we[2],
                                      wqkv_bf, we_bf);

    const float* tin = x;
    float* touts[3] = {tA, tB, tA};
    for (int l = 0; l < 3; ++l) {
        unfold_k<<<256, 256, 0, stream>>>(tin, cols_f, colsT, mu, rstd);
        mgemm_k<96, 3, 1, 64><<<dim3(64, 3, 4), 256, 0, stream>>>(
            wg_bf + (size_t)l * EE * DD, colsT, 288, xrT, nullptr,
            mu, rstd, wgsum + l * EE, wbeta + l * EE, nullptr, nullptr);
        mgemm_k<160, 1, 0, 128><<<dim3(32, 9, 4), 256, 0, stream>>>(
            wqkv_bf + (size_t)l * 432 * 160, xrT, 160, qkT, vF,
            nullptr, nullptr, nullptr, nullptr, nullptr, nullptr);
        attn_k2<<<1024, 256, 0, stream>>>(qkT, vF, oT);
        mgemm_k<160, 1, 2, 128><<<dim3(32, 6, 4), 256, 0, stream>>>(
            we_bf + (size_t)l * DD * 160, oT, 160, nullptr, nullptr,
            nullptr, nullptr, nullptr, nullptr, be[l], cols_f);
        fold_k<<<2048, 256, 0, stream>>>(cols_f, touts[l]);
        tin = touts[l];
    }
    conv_k<<<2048, 256, 0, stream>>>(tA, cw, cb, x, out);
}

// Round 6
// 517.968 us; speedup vs baseline: 3.0643x; 1.0203x over previous
//
#include <hip/hip_runtime.h>
#include <math.h>

#define BN 4
#define CC 32
#define HH 64
#define WW 64
#define DD 288          // C*K*K
#define EE 144
#define NTOK 4096
#define SCALE_F 0.2357022603955158f           // 18^-0.5
#define QSCALE  0.3401074286f                 // SCALE_F * log2(e)
#define QKST 384        // qkT row stride: 8 heads*24 Q | 8 heads*24 K
#define MQKV 528        // padded QKV GEMM M: 192 Q + 192 K + 144 V

typedef __bf16 bf16x8 __attribute__((ext_vector_type(8)));
typedef float floatx4 __attribute__((ext_vector_type(4)));
typedef unsigned short u16x8 __attribute__((ext_vector_type(8)));

__device__ __forceinline__ unsigned short f2bf(float x) {
    unsigned int u = __float_as_uint(x);
    u += 0x7fffu + ((u >> 16) & 1u);          // RNE
    return (unsigned short)(u >> 16);
}
// pack hi16(a), hi16(b) -> (b_hi<<16)|a_hi  — single v_perm_b32
__device__ __forceinline__ unsigned int pack_bf_trunc(float a, float b) {
    return __builtin_amdgcn_perm(__float_as_uint(b), __float_as_uint(a), 0x07060302u);
}

// ---------------- precompute LN-folded reduction weights (bf16) ----------------
__global__ void precompute_k(const float* __restrict__ wr0, const float* __restrict__ br0,
                             const float* __restrict__ wr1, const float* __restrict__ br1,
                             const float* __restrict__ wr2, const float* __restrict__ br2,
                             const float* __restrict__ g,  const float* __restrict__ lb,
                             unsigned short* __restrict__ wg_bf, float* __restrict__ wgsum,
                             float* __restrict__ wbeta)
{
    int l = blockIdx.x;
    int e = threadIdx.x;            // 144 threads
    const float* wr = (l == 0) ? wr0 : ((l == 1) ? wr1 : wr2);
    const float* br = (l == 0) ? br0 : ((l == 1) ? br1 : br2);
    float sg = 0.f, sb = 0.f;
    for (int d = 0; d < DD; ++d) {
        float w = wr[e * DD + d];
        float wgv = w * g[d];
        wg_bf[((size_t)l * EE + e) * DD + d] = f2bf(wgv);
        sg += wgv;
        sb += w * lb[d];
    }
    wgsum[l * EE + e] = sg;
    wbeta[l * EE + e] = sb + br[e];
}

// ---------------- convert wqkv (head-padded 18->24, Q rows pre-scaled) / we to bf16 ----------------
// wqkv_bf: [l][528][160]. rows 0..191: Q heads (24/head, cols>=18 zero), *QSCALE.
// rows 192..383: K heads padded. rows 384..527: V (unpadded). k padded 144->160.
__global__ __launch_bounds__(256) void convw_k(
    const float* __restrict__ wqkv0, const float* __restrict__ wqkv1, const float* __restrict__ wqkv2,
    const float* __restrict__ we0,   const float* __restrict__ we1,   const float* __restrict__ we2,
    unsigned short* __restrict__ wqkv_bf, unsigned short* __restrict__ we_bf)
{
    int idx = blockIdx.x * 256 + threadIdx.x;
    const int T1 = 3 * MQKV * 160;
    const int T2 = 3 * 288 * 160;
    if (idx < T1) {
        int l = idx / (MQKV * 160), r = idx % (MQKV * 160);
        int m = r / 160, k = r % 160;
        const float* w = (l == 0) ? wqkv0 : ((l == 1) ? wqkv1 : wqkv2);
        float v = 0.f;
        if (k < 144) {
            if (m < 192) {
                int h = m / 24, j = m % 24;
                if (j < 18) v = w[(h * 18 + j) * 144 + k] * QSCALE;
            } else if (m < 384) {
                int mm = m - 192, h = mm / 24, j = mm % 24;
                if (j < 18) v = w[(144 + h * 18 + j) * 144 + k];
            } else {
                v = w[(288 + (m - 384)) * 144 + k];
            }
        }
        wqkv_bf[idx] = f2bf(v);
    } else if (idx < T1 + T2) {
        int j = idx - T1;
        int l = j / (288 * 160), r = j % (288 * 160);
        int m = r / 160, k = r % 160;
        const float* w = (l == 0) ? we0 : ((l == 1) ? we1 : we2);
        we_bf[j] = (k < 144) ? f2bf(w[m * 144 + k]) : 0;
    }
}

// ---------------- unfold + LN stats + bf16 token-major copy ----------------
__global__ __launch_bounds__(256) void unfold_k(const float* __restrict__ t,
    float* __restrict__ cols_f, unsigned short* __restrict__ colsT,
    float* __restrict__ mu, float* __restrict__ rstd)
{
    __shared__ float red1[4][64], red2[4][64];
    int tid = threadIdx.x;
    int lane = tid & 63, cpart = tid >> 6;
    int b = blockIdx.x >> 6, nc = blockIdx.x & 63;
    int n = nc * 64 + lane;
    int h = n >> 6, w = n & 63;
    const float* tb = t + (size_t)b * CC * HH * WW;
    float* cf = cols_f + (size_t)b * DD * NTOK;
    unsigned short loc[72];
    float s1 = 0.f, s2 = 0.f;
    #pragma unroll
    for (int c8 = 0; c8 < 8; ++c8) {
        int c = cpart * 8 + c8;
        const float* tc = tb + (size_t)c * 4096;
        #pragma unroll
        for (int i = 0; i < 3; ++i) {
            int hr = h + i - 1;
            bool rok = ((unsigned)hr < 64u);
            #pragma unroll
            for (int j = 0; j < 3; ++j) {
                int wc = w + j - 1;
                bool ok = rok && ((unsigned)wc < 64u);
                float v = ok ? tc[hr * 64 + wc] : 0.f;
                cf[(size_t)(c * 9 + i * 3 + j) * NTOK + n] = v;
                loc[c8 * 9 + i * 3 + j] = f2bf(v);
                s1 += v;
                s2 = fmaf(v, v, s2);
            }
        }
    }
    unsigned short* ct = colsT + ((size_t)b * NTOK + n) * 288 + cpart * 72;
    #pragma unroll
    for (int u = 0; u < 9; ++u)
        *(u16x8*)&ct[u * 8] = *(const u16x8*)&loc[u * 8];
    red1[cpart][lane] = s1;
    red2[cpart][lane] = s2;
    __syncthreads();
    if (tid < 64) {
        float a = red1[0][tid] + red1[1][tid] + red1[2][tid] + red1[3][tid];
        float q = red2[0][tid] + red2[1][tid] + red2[2][tid] + red2[3][tid];
        float m = a * (1.f / 288.f);
        float var = q * (1.f / 288.f) - m * m;
        int nn = nc * 64 + tid;
        mu[b * NTOK + nn] = m;
        rstd[b * NTOK + nn] = rsqrtf(var + 1e-5f);
    }
}

// ---------------- bf16 MFMA GEMM: C[m][n] = sum_k A[m][k] * Bt[n][k] ----------------
// Tile 48xNT, 4 waves, mfma 16x16x32.
// MODE 1: LN epilogue + transpose-store xrT[tok][160] (+pad at m0==96).
// MODE 0: m0<384 -> transpose-store qkT[tok][384]; m0>=384 -> vF[144][4096] (NT=128).
// MODE 2: natural fp32 store +bias +residual in-place.
template<int BK, int NCHUNK, int MODE, int NT>
__global__ __launch_bounds__(256) void mgemm_k(
    const unsigned short* __restrict__ A, const unsigned short* __restrict__ Bt, int BST,
    unsigned short* __restrict__ Ct, unsigned short* __restrict__ Cv,
    const float* __restrict__ mu, const float* __restrict__ rstd,
    const float* __restrict__ wgsum, const float* __restrict__ wbeta,
    const float* __restrict__ bias, float* __restrict__ resid)
{
    constexpr int LDK = BK + 8;
    constexpr int AST = NCHUNK * BK;
    constexpr int NI  = NT / 64;
    __shared__ unsigned short smem[(48 + NT) * LDK];
    unsigned short* As = smem;
    unsigned short* Bs = smem + 48 * LDK;

    int n0 = blockIdx.x * NT;
    int m0 = blockIdx.y * 48;
    int bI = blockIdx.z;
    int tid = threadIdx.x;
    int wv = tid >> 6, lane = tid & 63;
    int l15 = lane & 15, l4 = lane >> 4;

    floatx4 acc[3][NI];
    #pragma unroll
    for (int mi = 0; mi < 3; ++mi)
        #pragma unroll
        for (int ni = 0; ni < NI; ++ni)
            acc[mi][ni] = (floatx4){0.f, 0.f, 0.f, 0.f};

    const unsigned short* Bb = Bt + (size_t)bI * NTOK * BST;

    for (int c = 0; c < NCHUNK; ++c) {
        if (c) __syncthreads();
        int k0 = c * BK;
        for (int u = tid; u < 48 * (BK / 8); u += 256) {
            int row = u / (BK / 8), seg = u % (BK / 8);
            *(u16x8*)&As[row * LDK + seg * 8] =
                *(const u16x8*)&A[(size_t)(m0 + row) * AST + k0 + seg * 8];
        }
        for (int u = tid; u < NT * (BK / 8); u += 256) {
            int row = u / (BK / 8), seg = u % (BK / 8);
            *(u16x8*)&Bs[row * LDK + seg * 8] =
                *(const u16x8*)&Bb[(size_t)(n0 + row) * BST + k0 + seg * 8];
        }
        __syncthreads();
        #pragma unroll
        for (int ks = 0; ks < BK / 32; ++ks) {
            bf16x8 af[3], bfr[NI];
            #pragma unroll
            for (int mi = 0; mi < 3; ++mi)
                af[mi] = *(const bf16x8*)&As[(mi * 16 + l15) * LDK + ks * 32 + l4 * 8];
            #pragma unroll
            for (int ni = 0; ni < NI; ++ni)
                bfr[ni] = *(const bf16x8*)&Bs[(wv * (NT / 4) + ni * 16 + l15) * LDK + ks * 32 + l4 * 8];
            #pragma unroll
            for (int mi = 0; mi < 3; ++mi)
                #pragma unroll
                for (int ni = 0; ni < NI; ++ni)
                    acc[mi][ni] = __builtin_amdgcn_mfma_f32_16x16x32_bf16(af[mi], bfr[ni], acc[mi][ni], 0, 0, 0);
        }
    }

    if (MODE == 2) {
        #pragma unroll
        for (int mi = 0; mi < 3; ++mi)
            #pragma unroll
            for (int r = 0; r < 4; ++r) {
                int m_g = m0 + mi * 16 + l4 * 4 + r;
                float bb = bias[m_g];
                #pragma unroll
                for (int ni = 0; ni < NI; ++ni) {
                    int n_g = n0 + wv * (NT / 4) + ni * 16 + l15;
                    size_t ci = ((size_t)bI * DD + m_g) * NTOK + n_g;
                    resid[ci] += acc[mi][ni][r] + bb;
                }
            }
    } else {
        __syncthreads();
        unsigned short* Ts = smem;
        bool vpath = (MODE == 0) && (m0 >= 384);
        float muv[NI], rsv[NI];
        if (MODE == 1) {
            #pragma unroll
            for (int ni = 0; ni < NI; ++ni) {
                int n_g = n0 + wv * (NT / 4) + ni * 16 + l15;
                muv[ni] = mu[bI * NTOK + n_g];
                rsv[ni] = rstd[bI * NTOK + n_g];
            }
        }
        #pragma unroll
        for (int mi = 0; mi < 3; ++mi)
            #pragma unroll
            for (int r = 0; r < 4; ++r) {
                int m_l = mi * 16 + l4 * 4 + r;
                float wgs = 0.f, wbv = 0.f;
                if (MODE == 1) { wgs = wgsum[m0 + m_l]; wbv = wbeta[m0 + m_l]; }
                #pragma unroll
                for (int ni = 0; ni < NI; ++ni) {
                    int n_l = wv * (NT / 4) + ni * 16 + l15;
                    float v = acc[mi][ni][r];
                    if (MODE == 1) v = rsv[ni] * (v - muv[ni] * wgs) + wbv;
                    if (!vpath) Ts[n_l * 56 + m_l] = f2bf(v);
                    else        Ts[m_l * 136 + n_l] = f2bf(v);
                }
            }
        __syncthreads();
        if (!vpath) {
            const int CTS = (MODE == 1) ? 160 : QKST;
            for (int rr = tid; rr < NT * 2; rr += 256) {
                int row = rr >> 1, half = rr & 1;
                unsigned short* dst = Ct + ((size_t)bI * NTOK + n0 + row) * CTS + m0 + half * 24;
                const unsigned short* src = &Ts[row * 56 + half * 24];
                #pragma unroll
                for (int u = 0; u < 3; ++u)
                    *(u16x8*)&dst[u * 8] = *(const u16x8*)&src[u * 8];
                if (MODE == 1 && m0 == 96) {
                    u16x8 z = (u16x8)0;
                    *(u16x8*)(Ct + ((size_t)bI * NTOK + n0 + row) * 160 + 144 + half * 8) = z;
                }
            }
        } else {
            if (tid < 192) {
                int m = tid >> 2, seg = tid & 3;
                unsigned short* dst = Cv + ((size_t)bI * EE + (m0 - 384) + m) * NTOK + n0 + seg * 32;
                const unsigned short* src = &Ts[m * 136 + seg * 32];
                #pragma unroll
                for (int u = 0; u < 4; ++u)
                    *(u16x8*)&dst[u * 8] = *(const u16x8*)&src[u * 8];
            }
        }
    }
}

// ---------------- MFMA bf16 attention ----------------
// qkT [b][tok][384] (Q head h at 24h, K at 192+24h; d>=18 zero, Q pre-scaled),
// vF [b][144][4096], oT [b][tok][160]. blk = qc*128 + bhs (XCD swizzle).
// Q frags load direct global->VGPR (no LDS). K staged b128 [tok][40]; V [d][136];
// P per-wave [q][72]; V pad-row d=31 = 1.0 -> row-sum l free.
__global__ __launch_bounds__(256) void attn_k2(const unsigned short* __restrict__ qkT,
                                               const unsigned short* __restrict__ vF,
                                               unsigned short* __restrict__ oT)
{
    __shared__ unsigned short Ks[128 * 40];       // [tok][d pad 40]
    __shared__ unsigned short Vs[32 * 136];       // [d][tok pad 136]
    __shared__ unsigned short Ps[4 * 32 * 72];    // per-wave [q][tok(64) pad 72]

    int blk = blockIdx.x;
    int bhs = blk & 127;
    int qc  = blk >> 7;
    int b = bhs >> 5, h = (bhs >> 2) & 7, s = bhs & 3;
    int tid  = threadIdx.x;
    int wv   = tid >> 6;
    int lane = tid & 63;
    int l15 = lane & 15, l4 = lane >> 4;
    int q0 = qc * 128;
    int tokbase = s * 1024;

    const unsigned short* qkb = qkT + (size_t)b * NTOK * QKST;

    // ---- init pads ----
    if (tid < 128) {
        u16x8 z = (u16x8)0;
        *(u16x8*)&Ks[tid * 40 + 24] = z;          // K cols 24..31
    } else {
        for (int v = tid - 128; v < 14 * 16; v += 128) {   // V rows 18..31
            int d = 18 + (v >> 4), seg = v & 15;
            unsigned short val = (d == 31) ? (unsigned short)0x3F80 : (unsigned short)0;
            u16x8 vv = (u16x8)val;
            *(u16x8*)&Vs[d * 136 + seg * 8] = vv;
        }
    }

    // ---- Q frags direct from global (d 24..31 masked to zero) ----
    bf16x8 qf[2];
    #pragma unroll
    for (int ni = 0; ni < 2; ++ni) {
        u16x8 raw = *(const u16x8*)(qkb + (size_t)(tokbase + q0 + wv * 32 + ni * 16 + l15) * QKST
                                    + 24 * h + l4 * 8);
        if (l4 == 3) raw = (u16x8)0;
        qf[ni] = *(bf16x8*)&raw;
    }

    floatx4 oacc[2][2];
    #pragma unroll
    for (int i = 0; i < 2; ++i)
        #pragma unroll
        for (int j = 0; j < 2; ++j)
            oacc[i][j] = (floatx4){0.f, 0.f, 0.f, 0.f};

    unsigned short* Pw = &Ps[wv * 32 * 72];

    for (int c0 = 0; c0 < 1024; c0 += 128) {
        __syncthreads();                     // prev readers done / init visible
        if (tid < 128) {                     // K: one tok/thread, 3 x b128
            int tok = tid;
            const unsigned short* src = qkb + (size_t)(tokbase + c0 + tok) * QKST + 192 + 24 * h;
            unsigned short* dk = &Ks[tok * 40];
            *(u16x8*)&dk[0]  = *(const u16x8*)&src[0];
            *(u16x8*)&dk[8]  = *(const u16x8*)&src[8];
            *(u16x8*)&dk[16] = *(const u16x8*)&src[16];   // d16,17 + zeros 18..23
        } else {                             // V rows d<18: 18 x 16 segs of 8 toks
            for (int idx = tid - 128; idx < 18 * 16; idx += 128) {
                int d = idx >> 4, seg = idx & 15;
                const unsigned short* src = vF + ((size_t)b * EE + h * 18 + d) * NTOK + tokbase + c0 + seg * 8;
                *(u16x8*)&Vs[d * 136 + seg * 8] = *(const u16x8*)src;
            }
        }
        __syncthreads();

        #pragma unroll
        for (int sub = 0; sub < 2; ++sub) {
            // S^T: m = token (4 tiles of 16), n = q (2 tiles)
            bf16x8 kf[4];
            #pragma unroll
            for (int mi = 0; mi < 4; ++mi)
                kf[mi] = *(const bf16x8*)&Ks[(sub * 64 + mi * 16 + l15) * 40 + l4 * 8];

            floatx4 sacc[4][2];
            #pragma unroll
            for (int mi = 0; mi < 4; ++mi)
                #pragma unroll
                for (int ni = 0; ni < 2; ++ni) {
                    floatx4 z = (floatx4){0.f, 0.f, 0.f, 0.f};
                    sacc[mi][ni] = __builtin_amdgcn_mfma_f32_16x16x32_bf16(kf[mi], qf[ni], z, 0, 0, 0);
                }

            // exp2 + truncation-pack -> wave-private P [q][tok64]
            #pragma unroll
            for (int mi = 0; mi < 4; ++mi)
                #pragma unroll
                for (int ni = 0; ni < 2; ++ni) {
                    int ql   = ni * 16 + l15;
                    int tokb = mi * 16 + l4 * 4;
                    unsigned int lo = pack_bf_trunc(exp2f(sacc[mi][ni][0]), exp2f(sacc[mi][ni][1]));
                    unsigned int hi = pack_bf_trunc(exp2f(sacc[mi][ni][2]), exp2f(sacc[mi][ni][3]));
                    uint2 pk = make_uint2(lo, hi);
                    *(uint2*)&Pw[ql * 72 + tokb] = pk;
                }

            // PV: m = q (2), n = d (2), k = token (2 steps of 32)
            #pragma unroll
            for (int ks = 0; ks < 2; ++ks) {
                bf16x8 pf[2], vf[2];
                pf[0] = *(const bf16x8*)&Pw[(     l15) * 72 + ks * 32 + l4 * 8];
                pf[1] = *(const bf16x8*)&Pw[(16 + l15) * 72 + ks * 32 + l4 * 8];
                vf[0] = *(const bf16x8*)&Vs[(     l15) * 136 + sub * 64 + ks * 32 + l4 * 8];
                vf[1] = *(const bf16x8*)&Vs[(16 + l15) * 136 + sub * 64 + ks * 32 + l4 * 8];
                #pragma unroll
                for (int mi = 0; mi < 2; ++mi)
                    #pragma unroll
                    for (int nd = 0; nd < 2; ++nd)
                        oacc[mi][nd] = __builtin_amdgcn_mfma_f32_16x16x32_bf16(pf[mi], vf[nd], oacc[mi][nd], 0, 0, 0);
            }
        }
    }

    // normalize by l (O col 31) -> fO [q][33] fp32 in dead P region (wave-private)
    float* fO = (float*)Pw;
    #pragma unroll
    for (int mi = 0; mi < 2; ++mi)
        #pragma unroll
        for (int r = 0; r < 4; ++r) {
            float lsum = __shfl(oacc[mi][1][r], (lane & 48) | 15, 64);
            float inv  = 1.f / lsum;
            int ql = mi * 16 + l4 * 4 + r;
            fO[ql * 33 + l15] = oacc[mi][0][r] * inv;
            if (l15 < 2) fO[ql * 33 + 16 + l15] = oacc[mi][1][r] * inv;
        }

    {
        int q = lane & 31, dh = lane >> 5;
        size_t rowi = (size_t)b * NTOK + tokbase + q0 + wv * 32 + q;
        unsigned short* orow = oT + rowi * 160 + h * 18;
        for (int i = dh; i < 9; i += 2) {
            float a  = fO[q * 33 + 2 * i];
            float bb = fO[q * 33 + 2 * i + 1];
            *(unsigned int*)&orow[2 * i] = (unsigned)f2bf(a) | ((unsigned)f2bf(bb) << 16);
        }
        if (h == 7) {
            u16x8 z = (u16x8)0;
            *(u16x8*)(oT + rowi * 160 + 144 + dh * 8) = z;
        }
    }
}

// ---------------- fold (scatter-add of 3x3 patches, crop) ----------------
__global__ __launch_bounds__(256) void fold_k(const float* __restrict__ cols, float* __restrict__ t)
{
    int idx = blockIdx.x * 256 + threadIdx.x;
    int w = idx & 63;
    int h = (idx >> 6) & 63;
    int c = (idx >> 12) & 31;
    int b = idx >> 17;
    const float* cb = cols + (size_t)b * DD * NTOK + (size_t)c * 9 * NTOK;
    float sum = 0.f;
    #pragma unroll
    for (int i = 0; i < 3; ++i) {
        int hs = h + 1 - i;
        if ((unsigned)hs < 64u) {
            #pragma unroll
            for (int j = 0; j < 3; ++j) {
                int ws_ = w + 1 - j;
                if ((unsigned)ws_ < 64u)
                    sum += cb[(size_t)(i * 3 + j) * NTOK + hs * 64 + ws_];
            }
        }
    }
    t[idx] = sum;
}

// ---------------- conv3x3 + ELU + residual ----------------
__global__ __launch_bounds__(256) void conv_k(const float* __restrict__ t,
    const float* __restrict__ cw, const float* __restrict__ cbias,
    const float* __restrict__ x, float* __restrict__ out)
{
    __shared__ float wsh[CC * 9];
    int idx = blockIdx.x * 256 + threadIdx.x;
    int w = idx & 63;
    int h = (idx >> 6) & 63;
    int co = (idx >> 12) & 31;
    int b = idx >> 17;
    int tid = threadIdx.x;
    for (int u = tid; u < CC * 9; u += 256) wsh[u] = cw[co * CC * 9 + u];
    __syncthreads();
    const float* tb = t + (size_t)b * CC * HH * WW;
    float acc = cbias[co];
    for (int ci = 0; ci < CC; ++ci) {
        const float* tc = tb + (size_t)ci * HH * WW;
        const float* wrow = &wsh[ci * 9];
        #pragma unroll
        for (int i = 0; i < 3; ++i) {
            int hr = h + i - 1;
            if ((unsigned)hr < 64u) {
                #pragma unroll
                for (int j = 0; j < 3; ++j) {
                    int wc = w + j - 1;
                    if ((unsigned)wc < 64u)
                        acc = fmaf(wrow[i * 3 + j], tc[hr * 64 + wc], acc);
                }
            }
        }
    }
    float e = (acc > 0.f) ? acc : (__expf(acc) - 1.f);
    out[idx] = x[idx] + e;
}

extern "C" void kernel_launch(void* const* d_in, const int* in_sizes, int n_in,
                              void* d_out, int out_size, void* d_ws, size_t ws_size,
                              hipStream_t stream)
{
    const float* x    = (const float*)d_in[0];
    const float* ln_g = (const float*)d_in[1];
    const float* ln_b = (const float*)d_in[2];
    const float* cw   = (const float*)d_in[3];
    const float* cb   = (const float*)d_in[4];
    const float* wr[3]   = {(const float*)d_in[5],  (const float*)d_in[10], (const float*)d_in[15]};
    const float* br[3]   = {(const float*)d_in[6],  (const float*)d_in[11], (const float*)d_in[16]};
    const float* wqkv[3] = {(const float*)d_in[7],  (const float*)d_in[12], (const float*)d_in[17]};
    const float* we[3]   = {(const float*)d_in[8],  (const float*)d_in[13], (const float*)d_in[18]};
    const float* be[3]   = {(const float*)d_in[9],  (const float*)d_in[14], (const float*)d_in[19]};
    float* out = (float*)d_out;

    char* p = (char*)d_ws;
    float* cols_f = (float*)p;            p += (size_t)BN * DD * NTOK * 4;        // 18.9 MB
    unsigned short* colsT = (unsigned short*)p; p += (size_t)BN * NTOK * 288 * 2; // 9.4 MB
    unsigned short* oT = colsT;           // alias: colsT dead once GEMM1 ran; oT dead before next unfold
    unsigned short* xrT   = (unsigned short*)p; p += (size_t)BN * NTOK * 160 * 2; // 5.2 MB
    unsigned short* qkT   = (unsigned short*)p; p += (size_t)BN * NTOK * QKST * 2;// 12.6 MB
    unsigned short* vF    = (unsigned short*)p; p += (size_t)BN * EE * NTOK * 2;  // 4.7 MB
    float* mu   = (float*)p;              p += (size_t)BN * NTOK * 4;
    float* rstd = (float*)p;              p += (size_t)BN * NTOK * 4;
    float* tA   = (float*)p;              p += (size_t)BN * CC * HH * WW * 4;
    float* tB   = (float*)p;              p += (size_t)BN * CC * HH * WW * 4;
    unsigned short* wg_bf   = (unsigned short*)p; p += (size_t)3 * EE * DD * 2;
    unsigned short* wqkv_bf = (unsigned short*)p; p += (size_t)3 * MQKV * 160 * 2;
    unsigned short* we_bf   = (unsigned short*)p; p += (size_t)3 * DD * 160 * 2;
    float* wgsum = (float*)p;             p += 3 * EE * 4;
    float* wbeta = (float*)p;             p += 3 * EE * 4;
    (void)in_sizes; (void)n_in; (void)out_size; (void)ws_size;

    precompute_k<<<3, 144, 0, stream>>>(wr[0], br[0], wr[1], br[1], wr[2], br[2],
                                        ln_g, ln_b, wg_bf, wgsum, wbeta);
    convw_k<<<1530, 256, 0, stream>>>(wqkv[0], wqkv[1], wqkv[2], we[0], we[1], we[2],
                                      wqkv_bf, we_bf);

    const float* tin = x;
    float* touts[3] = {tA, tB, tA};
    for (int l = 0; l < 3; ++l) {
        unfold_k<<<256, 256, 0, stream>>>(tin, cols_f, colsT, mu, rstd);
        mgemm_k<96, 3, 1, 64><<<dim3(64, 3, 4), 256, 0, stream>>>(
            wg_bf + (size_t)l * EE * DD, colsT, 288, xrT, nullptr,
            mu, rstd, wgsum + l * EE, wbeta + l * EE, nullptr, nullptr);
        mgemm_k<160, 1, 0, 128><<<dim3(32, 11, 4), 256, 0, stream>>>(
            wqkv_bf + (size_t)l * MQKV * 160, xrT, 160, qkT, vF,
            nullptr, nullptr, nullptr, nullptr, nullptr, nullptr);
        attn_k2<<<1024, 256, 0, stream>>>(qkT, vF, oT);
        mgemm_k<160, 1, 2, 128><<<dim3(32, 6, 4), 256, 0, stream>>>(
            we_bf + (size_t)l * DD * 160, oT, 160, nullptr, nullptr,
            nullptr, nullptr, nullptr, nullptr, be[l], cols_f);
        fold_k<<<2048, 256, 0, stream>>>(cols_f, touts[l]);
        tin = touts[l];
    }
    conv_k<<<2048, 256, 0, stream>>>(tA, cw, cb, x, out);
}

// Round 7
// 463.305 us; speedup vs baseline: 3.4258x; 1.1180x over previous
//
#include <hip/hip_runtime.h>
#include <math.h>

#define BN 4
#define CC 32
#define HH 64
#define WW 64
#define DD 288          // C*K*K
#define EE 144
#define NTOK 4096
#define SCALE_F 0.2357022603955158f           // 18^-0.5
#define QSCALE  0.3401074286f                 // SCALE_F * log2(e)
#define QKST 384        // qkT row stride: 8 heads*24 Q | 8 heads*24 K
#define MQKV 528        // padded QKV GEMM M: 192 Q + 192 K + 144 V

typedef __bf16 bf16x8 __attribute__((ext_vector_type(8)));
typedef float floatx4 __attribute__((ext_vector_type(4)));
typedef unsigned short u16x8 __attribute__((ext_vector_type(8)));

__device__ __forceinline__ unsigned short f2bf(float x) {
    unsigned int u = __float_as_uint(x);
    u += 0x7fffu + ((u >> 16) & 1u);          // RNE
    return (unsigned short)(u >> 16);
}
// pack hi16(a), hi16(b) -> (b_hi<<16)|a_hi  — single v_perm_b32
__device__ __forceinline__ unsigned int pack_bf_trunc(float a, float b) {
    return __builtin_amdgcn_perm(__float_as_uint(b), __float_as_uint(a), 0x07060302u);
}

// ---------------- precompute LN-folded reduction weights (bf16) ----------------
__global__ void precompute_k(const float* __restrict__ wr0, const float* __restrict__ br0,
                             const float* __restrict__ wr1, const float* __restrict__ br1,
                             const float* __restrict__ wr2, const float* __restrict__ br2,
                             const float* __restrict__ g,  const float* __restrict__ lb,
                             unsigned short* __restrict__ wg_bf, float* __restrict__ wgsum,
                             float* __restrict__ wbeta)
{
    int l = blockIdx.x;
    int e = threadIdx.x;            // 144 threads
    const float* wr = (l == 0) ? wr0 : ((l == 1) ? wr1 : wr2);
    const float* br = (l == 0) ? br0 : ((l == 1) ? br1 : br2);
    float sg = 0.f, sb = 0.f;
    for (int d = 0; d < DD; ++d) {
        float w = wr[e * DD + d];
        float wgv = w * g[d];
        wg_bf[((size_t)l * EE + e) * DD + d] = f2bf(wgv);
        sg += wgv;
        sb += w * lb[d];
    }
    wgsum[l * EE + e] = sg;
    wbeta[l * EE + e] = sb + br[e];
}

// ---------------- convert wqkv (head-padded 18->24, Q rows pre-scaled) / we to bf16 ----------------
__global__ __launch_bounds__(256) void convw_k(
    const float* __restrict__ wqkv0, const float* __restrict__ wqkv1, const float* __restrict__ wqkv2,
    const float* __restrict__ we0,   const float* __restrict__ we1,   const float* __restrict__ we2,
    unsigned short* __restrict__ wqkv_bf, unsigned short* __restrict__ we_bf)
{
    int idx = blockIdx.x * 256 + threadIdx.x;
    const int T1 = 3 * MQKV * 160;
    const int T2 = 3 * 288 * 160;
    if (idx < T1) {
        int l = idx / (MQKV * 160), r = idx % (MQKV * 160);
        int m = r / 160, k = r % 160;
        const float* w = (l == 0) ? wqkv0 : ((l == 1) ? wqkv1 : wqkv2);
        float v = 0.f;
        if (k < 144) {
            if (m < 192) {
                int h = m / 24, j = m % 24;
                if (j < 18) v = w[(h * 18 + j) * 144 + k] * QSCALE;
            } else if (m < 384) {
                int mm = m - 192, h = mm / 24, j = mm % 24;
                if (j < 18) v = w[(144 + h * 18 + j) * 144 + k];
            } else {
                v = w[(288 + (m - 384)) * 144 + k];
            }
        }
        wqkv_bf[idx] = f2bf(v);
    } else if (idx < T1 + T2) {
        int j = idx - T1;
        int l = j / (288 * 160), r = j % (288 * 160);
        int m = r / 160, k = r % 160;
        const float* w = (l == 0) ? we0 : ((l == 1) ? we1 : we2);
        we_bf[j] = (k < 144) ? f2bf(w[m * 144 + k]) : 0;
    }
}

// ---------------- unfold + LN stats -> bf16 token-major only ----------------
__global__ __launch_bounds__(256) void unfold_k(const float* __restrict__ t,
    unsigned short* __restrict__ colsT,
    float* __restrict__ mu, float* __restrict__ rstd)
{
    __shared__ float red1[4][64], red2[4][64];
    int tid = threadIdx.x;
    int lane = tid & 63, cpart = tid >> 6;
    int b = blockIdx.x >> 6, nc = blockIdx.x & 63;
    int n = nc * 64 + lane;
    int h = n >> 6, w = n & 63;
    const float* tb = t + (size_t)b * CC * HH * WW;
    unsigned short loc[72];
    float s1 = 0.f, s2 = 0.f;
    #pragma unroll
    for (int c8 = 0; c8 < 8; ++c8) {
        int c = cpart * 8 + c8;
        const float* tc = tb + (size_t)c * 4096;
        #pragma unroll
        for (int i = 0; i < 3; ++i) {
            int hr = h + i - 1;
            bool rok = ((unsigned)hr < 64u);
            #pragma unroll
            for (int j = 0; j < 3; ++j) {
                int wc = w + j - 1;
                bool ok = rok && ((unsigned)wc < 64u);
                float v = ok ? tc[hr * 64 + wc] : 0.f;
                loc[c8 * 9 + i * 3 + j] = f2bf(v);
                s1 += v;
                s2 = fmaf(v, v, s2);
            }
        }
    }
    unsigned short* ct = colsT + ((size_t)b * NTOK + n) * 288 + cpart * 72;
    #pragma unroll
    for (int u = 0; u < 9; ++u)
        *(u16x8*)&ct[u * 8] = *(const u16x8*)&loc[u * 8];
    red1[cpart][lane] = s1;
    red2[cpart][lane] = s2;
    __syncthreads();
    if (tid < 64) {
        float a = red1[0][tid] + red1[1][tid] + red1[2][tid] + red1[3][tid];
        float q = red2[0][tid] + red2[1][tid] + red2[2][tid] + red2[3][tid];
        float m = a * (1.f / 288.f);
        float var = q * (1.f / 288.f) - m * m;
        int nn = nc * 64 + tid;
        mu[b * NTOK + nn] = m;
        rstd[b * NTOK + nn] = rsqrtf(var + 1e-5f);
    }
}

// ---------------- bf16 MFMA GEMM: C[m][n] = sum_k A[m][k] * Bt[n][k] ----------------
// MODE 1: LN epilogue + transpose-store xrT[tok][160] (+pad at m0==96).
// MODE 0: m0<384 -> transpose-store qkT[tok][384]; m0>=384 -> vF[144][4096] (NT=128).
// MODE 2: natural fp32 PURE store +bias (residual handled in fold via mask).
template<int BK, int NCHUNK, int MODE, int NT>
__global__ __launch_bounds__(256) void mgemm_k(
    const unsigned short* __restrict__ A, const unsigned short* __restrict__ Bt, int BST,
    unsigned short* __restrict__ Ct, unsigned short* __restrict__ Cv,
    const float* __restrict__ mu, const float* __restrict__ rstd,
    const float* __restrict__ wgsum, const float* __restrict__ wbeta,
    const float* __restrict__ bias, float* __restrict__ resid)
{
    constexpr int LDK = BK + 8;
    constexpr int AST = NCHUNK * BK;
    constexpr int NI  = NT / 64;
    __shared__ unsigned short smem[(48 + NT) * LDK];
    unsigned short* As = smem;
    unsigned short* Bs = smem + 48 * LDK;

    int n0 = blockIdx.x * NT;
    int m0 = blockIdx.y * 48;
    int bI = blockIdx.z;
    int tid = threadIdx.x;
    int wv = tid >> 6, lane = tid & 63;
    int l15 = lane & 15, l4 = lane >> 4;

    floatx4 acc[3][NI];
    #pragma unroll
    for (int mi = 0; mi < 3; ++mi)
        #pragma unroll
        for (int ni = 0; ni < NI; ++ni)
            acc[mi][ni] = (floatx4){0.f, 0.f, 0.f, 0.f};

    const unsigned short* Bb = Bt + (size_t)bI * NTOK * BST;

    for (int c = 0; c < NCHUNK; ++c) {
        if (c) __syncthreads();
        int k0 = c * BK;
        for (int u = tid; u < 48 * (BK / 8); u += 256) {
            int row = u / (BK / 8), seg = u % (BK / 8);
            *(u16x8*)&As[row * LDK + seg * 8] =
                *(const u16x8*)&A[(size_t)(m0 + row) * AST + k0 + seg * 8];
        }
        for (int u = tid; u < NT * (BK / 8); u += 256) {
            int row = u / (BK / 8), seg = u % (BK / 8);
            *(u16x8*)&Bs[row * LDK + seg * 8] =
                *(const u16x8*)&Bb[(size_t)(n0 + row) * BST + k0 + seg * 8];
        }
        __syncthreads();
        #pragma unroll
        for (int ks = 0; ks < BK / 32; ++ks) {
            bf16x8 af[3], bfr[NI];
            #pragma unroll
            for (int mi = 0; mi < 3; ++mi)
                af[mi] = *(const bf16x8*)&As[(mi * 16 + l15) * LDK + ks * 32 + l4 * 8];
            #pragma unroll
            for (int ni = 0; ni < NI; ++ni)
                bfr[ni] = *(const bf16x8*)&Bs[(wv * (NT / 4) + ni * 16 + l15) * LDK + ks * 32 + l4 * 8];
            #pragma unroll
            for (int mi = 0; mi < 3; ++mi)
                #pragma unroll
                for (int ni = 0; ni < NI; ++ni)
                    acc[mi][ni] = __builtin_amdgcn_mfma_f32_16x16x32_bf16(af[mi], bfr[ni], acc[mi][ni], 0, 0, 0);
        }
    }

    if (MODE == 2) {
        #pragma unroll
        for (int mi = 0; mi < 3; ++mi)
            #pragma unroll
            for (int r = 0; r < 4; ++r) {
                int m_g = m0 + mi * 16 + l4 * 4 + r;
                float bb = bias[m_g];
                #pragma unroll
                for (int ni = 0; ni < NI; ++ni) {
                    int n_g = n0 + wv * (NT / 4) + ni * 16 + l15;
                    size_t ci = ((size_t)bI * DD + m_g) * NTOK + n_g;
                    resid[ci] = acc[mi][ni][r] + bb;
                }
            }
    } else {
        __syncthreads();
        unsigned short* Ts = smem;
        bool vpath = (MODE == 0) && (m0 >= 384);
        float muv[NI], rsv[NI];
        if (MODE == 1) {
            #pragma unroll
            for (int ni = 0; ni < NI; ++ni) {
                int n_g = n0 + wv * (NT / 4) + ni * 16 + l15;
                muv[ni] = mu[bI * NTOK + n_g];
                rsv[ni] = rstd[bI * NTOK + n_g];
            }
        }
        #pragma unroll
        for (int mi = 0; mi < 3; ++mi)
            #pragma unroll
            for (int r = 0; r < 4; ++r) {
                int m_l = mi * 16 + l4 * 4 + r;
                float wgs = 0.f, wbv = 0.f;
                if (MODE == 1) { wgs = wgsum[m0 + m_l]; wbv = wbeta[m0 + m_l]; }
                #pragma unroll
                for (int ni = 0; ni < NI; ++ni) {
                    int n_l = wv * (NT / 4) + ni * 16 + l15;
                    float v = acc[mi][ni][r];
                    if (MODE == 1) v = rsv[ni] * (v - muv[ni] * wgs) + wbv;
                    if (!vpath) Ts[n_l * 56 + m_l] = f2bf(v);
                    else        Ts[m_l * 136 + n_l] = f2bf(v);
                }
            }
        __syncthreads();
        if (!vpath) {
            const int CTS = (MODE == 1) ? 160 : QKST;
            for (int rr = tid; rr < NT * 2; rr += 256) {
                int row = rr >> 1, half = rr & 1;
                unsigned short* dst = Ct + ((size_t)bI * NTOK + n0 + row) * CTS + m0 + half * 24;
                const unsigned short* src = &Ts[row * 56 + half * 24];
                #pragma unroll
                for (int u = 0; u < 3; ++u)
                    *(u16x8*)&dst[u * 8] = *(const u16x8*)&src[u * 8];
                if (MODE == 1 && m0 == 96) {
                    u16x8 z = (u16x8)0;
                    *(u16x8*)(Ct + ((size_t)bI * NTOK + n0 + row) * 160 + 144 + half * 8) = z;
                }
            }
        } else {
            if (tid < 192) {
                int m = tid >> 2, seg = tid & 3;
                unsigned short* dst = Cv + ((size_t)bI * EE + (m0 - 384) + m) * NTOK + n0 + seg * 32;
                const unsigned short* src = &Ts[m * 136 + seg * 32];
                #pragma unroll
                for (int u = 0; u < 4; ++u)
                    *(u16x8*)&dst[u * 8] = *(const u16x8*)&src[u * 8];
            }
        }
    }
}

// ---------------- MFMA bf16 attention (unchanged from R6) ----------------
__global__ __launch_bounds__(256) void attn_k2(const unsigned short* __restrict__ qkT,
                                               const unsigned short* __restrict__ vF,
                                               unsigned short* __restrict__ oT)
{
    __shared__ unsigned short Ks[128 * 40];       // [tok][d pad 40]
    __shared__ unsigned short Vs[32 * 136];       // [d][tok pad 136]
    __shared__ unsigned short Ps[4 * 32 * 72];    // per-wave [q][tok(64) pad 72]

    int blk = blockIdx.x;
    int bhs = blk & 127;
    int qc  = blk >> 7;
    int b = bhs >> 5, h = (bhs >> 2) & 7, s = bhs & 3;
    int tid  = threadIdx.x;
    int wv   = tid >> 6;
    int lane = tid & 63;
    int l15 = lane & 15, l4 = lane >> 4;
    int q0 = qc * 128;
    int tokbase = s * 1024;

    const unsigned short* qkb = qkT + (size_t)b * NTOK * QKST;

    if (tid < 128) {
        u16x8 z = (u16x8)0;
        *(u16x8*)&Ks[tid * 40 + 24] = z;          // K cols 24..31
    } else {
        for (int v = tid - 128; v < 14 * 16; v += 128) {   // V rows 18..31
            int d = 18 + (v >> 4), seg = v & 15;
            unsigned short val = (d == 31) ? (unsigned short)0x3F80 : (unsigned short)0;
            u16x8 vv = (u16x8)val;
            *(u16x8*)&Vs[d * 136 + seg * 8] = vv;
        }
    }

    bf16x8 qf[2];
    #pragma unroll
    for (int ni = 0; ni < 2; ++ni) {
        u16x8 raw = *(const u16x8*)(qkb + (size_t)(tokbase + q0 + wv * 32 + ni * 16 + l15) * QKST
                                    + 24 * h + l4 * 8);
        if (l4 == 3) raw = (u16x8)0;
        qf[ni] = *(bf16x8*)&raw;
    }

    floatx4 oacc[2][2];
    #pragma unroll
    for (int i = 0; i < 2; ++i)
        #pragma unroll
        for (int j = 0; j < 2; ++j)
            oacc[i][j] = (floatx4){0.f, 0.f, 0.f, 0.f};

    unsigned short* Pw = &Ps[wv * 32 * 72];

    for (int c0 = 0; c0 < 1024; c0 += 128) {
        __syncthreads();
        if (tid < 128) {
            int tok = tid;
            const unsigned short* src = qkb + (size_t)(tokbase + c0 + tok) * QKST + 192 + 24 * h;
            unsigned short* dk = &Ks[tok * 40];
            *(u16x8*)&dk[0]  = *(const u16x8*)&src[0];
            *(u16x8*)&dk[8]  = *(const u16x8*)&src[8];
            *(u16x8*)&dk[16] = *(const u16x8*)&src[16];
        } else {
            for (int idx = tid - 128; idx < 18 * 16; idx += 128) {
                int d = idx >> 4, seg = idx & 15;
                const unsigned short* src = vF + ((size_t)b * EE + h * 18 + d) * NTOK + tokbase + c0 + seg * 8;
                *(u16x8*)&Vs[d * 136 + seg * 8] = *(const u16x8*)src;
            }
        }
        __syncthreads();

        #pragma unroll
        for (int sub = 0; sub < 2; ++sub) {
            bf16x8 kf[4];
            #pragma unroll
            for (int mi = 0; mi < 4; ++mi)
                kf[mi] = *(const bf16x8*)&Ks[(sub * 64 + mi * 16 + l15) * 40 + l4 * 8];

            floatx4 sacc[4][2];
            #pragma unroll
            for (int mi = 0; mi < 4; ++mi)
                #pragma unroll
                for (int ni = 0; ni < 2; ++ni) {
                    floatx4 z = (floatx4){0.f, 0.f, 0.f, 0.f};
                    sacc[mi][ni] = __builtin_amdgcn_mfma_f32_16x16x32_bf16(kf[mi], qf[ni], z, 0, 0, 0);
                }

            #pragma unroll
            for (int mi = 0; mi < 4; ++mi)
                #pragma unroll
                for (int ni = 0; ni < 2; ++ni) {
                    int ql   = ni * 16 + l15;
                    int tokb = mi * 16 + l4 * 4;
                    unsigned int lo = pack_bf_trunc(exp2f(sacc[mi][ni][0]), exp2f(sacc[mi][ni][1]));
                    unsigned int hi = pack_bf_trunc(exp2f(sacc[mi][ni][2]), exp2f(sacc[mi][ni][3]));
                    uint2 pk = make_uint2(lo, hi);
                    *(uint2*)&Pw[ql * 72 + tokb] = pk;
                }

            #pragma unroll
            for (int ks = 0; ks < 2; ++ks) {
                bf16x8 pf[2], vf[2];
                pf[0] = *(const bf16x8*)&Pw[(     l15) * 72 + ks * 32 + l4 * 8];
                pf[1] = *(const bf16x8*)&Pw[(16 + l15) * 72 + ks * 32 + l4 * 8];
                vf[0] = *(const bf16x8*)&Vs[(     l15) * 136 + sub * 64 + ks * 32 + l4 * 8];
                vf[1] = *(const bf16x8*)&Vs[(16 + l15) * 136 + sub * 64 + ks * 32 + l4 * 8];
                #pragma unroll
                for (int mi = 0; mi < 2; ++mi)
                    #pragma unroll
                    for (int nd = 0; nd < 2; ++nd)
                        oacc[mi][nd] = __builtin_amdgcn_mfma_f32_16x16x32_bf16(pf[mi], vf[nd], oacc[mi][nd], 0, 0, 0);
            }
        }
    }

    float* fO = (float*)Pw;
    #pragma unroll
    for (int mi = 0; mi < 2; ++mi)
        #pragma unroll
        for (int r = 0; r < 4; ++r) {
            float lsum = __shfl(oacc[mi][1][r], (lane & 48) | 15, 64);
            float inv  = 1.f / lsum;
            int ql = mi * 16 + l4 * 4 + r;
            fO[ql * 33 + l15] = oacc[mi][0][r] * inv;
            if (l15 < 2) fO[ql * 33 + 16 + l15] = oacc[mi][1][r] * inv;
        }

    {
        int q = lane & 31, dh = lane >> 5;
        size_t rowi = (size_t)b * NTOK + tokbase + q0 + wv * 32 + q;
        unsigned short* orow = oT + rowi * 160 + h * 18;
        for (int i = dh; i < 9; i += 2) {
            float a  = fO[q * 33 + 2 * i];
            float bb = fO[q * 33 + 2 * i + 1];
            *(unsigned int*)&orow[2 * i] = (unsigned)f2bf(a) | ((unsigned)f2bf(bb) << 16);
        }
        if (h == 7) {
            u16x8 z = (u16x8)0;
            *(u16x8*)(oT + rowi * 160 + 144 + dh * 8) = z;
        }
    }
}

// ---------------- fold + masked residual: t = fold(cols) + cnt(h)*cnt(w)*tprev ----------------
__global__ __launch_bounds__(256) void fold_k(const float* __restrict__ cols,
                                              const float* __restrict__ tprev,
                                              float* __restrict__ t)
{
    int idx = blockIdx.x * 256 + threadIdx.x;
    int w = idx & 63;
    int h = (idx >> 6) & 63;
    int c = (idx >> 12) & 31;
    int b = idx >> 17;
    const float* cb = cols + (size_t)b * DD * NTOK + (size_t)c * 9 * NTOK;
    float sum = 0.f;
    #pragma unroll
    for (int i = 0; i < 3; ++i) {
        int hs = h + 1 - i;
        if ((unsigned)hs < 64u) {
            #pragma unroll
            for (int j = 0; j < 3; ++j) {
                int ws_ = w + 1 - j;
                if ((unsigned)ws_ < 64u)
                    sum += cb[(size_t)(i * 3 + j) * NTOK + hs * 64 + ws_];
            }
        }
    }
    int ch = (h == 0 || h == 63) ? 2 : 3;
    int cw_ = (w == 0 || w == 63) ? 2 : 3;
    t[idx] = sum + (float)(ch * cw_) * tprev[idx];
}

// ---------------- conv3x3 + ELU + residual, 4-pixel register strips ----------------
// 512 blocks: b(2)|co(5)|band(2). Thread = 4-pixel row strip; co uniform -> weights LDS.
__global__ __launch_bounds__(256) void conv_k(const float* __restrict__ t,
    const float* __restrict__ cw, const float* __restrict__ cbias,
    const float* __restrict__ x, float* __restrict__ out)
{
    __shared__ float wsh[CC * 9];
    int blk = blockIdx.x;
    int band = blk & 3, co = (blk >> 2) & 31, b = blk >> 7;
    int tid = threadIdx.x;
    for (int u = tid; u < CC * 9; u += 256) wsh[u] = cw[co * CC * 9 + u];
    __syncthreads();
    int h = band * 16 + (tid >> 4);
    int w0 = (tid & 15) << 2;
    const float* tb = t + (size_t)b * CC * 4096;
    float bias = cbias[co];
    float a0 = bias, a1 = bias, a2 = bias, a3 = bias;
    for (int ci = 0; ci < CC; ++ci) {
        const float* tc = tb + (size_t)ci * 4096;
        const float* wr = &wsh[ci * 9];
        #pragma unroll
        for (int i = 0; i < 3; ++i) {
            int hr = h + i - 1;
            if ((unsigned)hr < 64u) {
                const float* row = tc + hr * 64;
                float vl = (w0 > 0)  ? row[w0 - 1] : 0.f;
                float4 c4 = *(const float4*)&row[w0];
                float vr = (w0 < 60) ? row[w0 + 4] : 0.f;
                float wj0 = wr[i * 3], wj1 = wr[i * 3 + 1], wj2 = wr[i * 3 + 2];
                a0 = fmaf(wj0, vl,   a0); a0 = fmaf(wj1, c4.x, a0); a0 = fmaf(wj2, c4.y, a0);
                a1 = fmaf(wj0, c4.x, a1); a1 = fmaf(wj1, c4.y, a1); a1 = fmaf(wj2, c4.z, a1);
                a2 = fmaf(wj0, c4.y, a2); a2 = fmaf(wj1, c4.z, a2); a2 = fmaf(wj2, c4.w, a2);
                a3 = fmaf(wj0, c4.z, a3); a3 = fmaf(wj1, c4.w, a3); a3 = fmaf(wj2, vr,   a3);
            }
        }
    }
    size_t oidx = ((size_t)(b * CC + co) * 4096) + h * 64 + w0;
    float4 xin = *(const float4*)&x[oidx];
    float4 o;
    o.x = xin.x + ((a0 > 0.f) ? a0 : (__expf(a0) - 1.f));
    o.y = xin.y + ((a1 > 0.f) ? a1 : (__expf(a1) - 1.f));
    o.z = xin.z + ((a2 > 0.f) ? a2 : (__expf(a2) - 1.f));
    o.w = xin.w + ((a3 > 0.f) ? a3 : (__expf(a3) - 1.f));
    *(float4*)&out[oidx] = o;
}

extern "C" void kernel_launch(void* const* d_in, const int* in_sizes, int n_in,
                              void* d_out, int out_size, void* d_ws, size_t ws_size,
                              hipStream_t stream)
{
    const float* x    = (const float*)d_in[0];
    const float* ln_g = (const float*)d_in[1];
    const float* ln_b = (const float*)d_in[2];
    const float* cw   = (const float*)d_in[3];
    const float* cb   = (const float*)d_in[4];
    const float* wr[3]   = {(const float*)d_in[5],  (const float*)d_in[10], (const float*)d_in[15]};
    const float* br[3]   = {(const float*)d_in[6],  (const float*)d_in[11], (const float*)d_in[16]};
    const float* wqkv[3] = {(const float*)d_in[7],  (const float*)d_in[12], (const float*)d_in[17]};
    const float* we[3]   = {(const float*)d_in[8],  (const float*)d_in[13], (const float*)d_in[18]};
    const float* be[3]   = {(const float*)d_in[9],  (const float*)d_in[14], (const float*)d_in[19]};
    float* out = (float*)d_out;

    char* p = (char*)d_ws;
    float* cols_f = (float*)p;            p += (size_t)BN * DD * NTOK * 4;        // 18.9 MB (emha out)
    unsigned short* colsT = (unsigned short*)p; p += (size_t)BN * NTOK * 288 * 2; // 9.4 MB
    unsigned short* oT = colsT;           // alias: disjoint lifetimes
    unsigned short* xrT   = (unsigned short*)p; p += (size_t)BN * NTOK * 160 * 2; // 5.2 MB
    unsigned short* qkT   = (unsigned short*)p; p += (size_t)BN * NTOK * QKST * 2;// 12.6 MB
    unsigned short* vF    = (unsigned short*)p; p += (size_t)BN * EE * NTOK * 2;  // 4.7 MB
    float* mu   = (float*)p;              p += (size_t)BN * NTOK * 4;
    float* rstd = (float*)p;              p += (size_t)BN * NTOK * 4;
    float* tA   = (float*)p;              p += (size_t)BN * CC * HH * WW * 4;
    float* tB   = (float*)p;              p += (size_t)BN * CC * HH * WW * 4;
    unsigned short* wg_bf   = (unsigned short*)p; p += (size_t)3 * EE * DD * 2;
    unsigned short* wqkv_bf = (unsigned short*)p; p += (size_t)3 * MQKV * 160 * 2;
    unsigned short* we_bf   = (unsigned short*)p; p += (size_t)3 * DD * 160 * 2;
    float* wgsum = (float*)p;             p += 3 * EE * 4;
    float* wbeta = (float*)p;             p += 3 * EE * 4;
    (void)in_sizes; (void)n_in; (void)out_size; (void)ws_size;

    precompute_k<<<3, 144, 0, stream>>>(wr[0], br[0], wr[1], br[1], wr[2], br[2],
                                        ln_g, ln_b, wg_bf, wgsum, wbeta);
    convw_k<<<1530, 256, 0, stream>>>(wqkv[0], wqkv[1], wqkv[2], we[0], we[1], we[2],
                                      wqkv_bf, we_bf);

    const float* tin = x;
    float* touts[3] = {tA, tB, tA};
    for (int l = 0; l < 3; ++l) {
        unfold_k<<<256, 256, 0, stream>>>(tin, colsT, mu, rstd);
        mgemm_k<96, 3, 1, 64><<<dim3(64, 3, 4), 256, 0, stream>>>(
            wg_bf + (size_t)l * EE * DD, colsT, 288, xrT, nullptr,
            mu, rstd, wgsum + l * EE, wbeta + l * EE, nullptr, nullptr);
        mgemm_k<160, 1, 0, 128><<<dim3(32, 11, 4), 256, 0, stream>>>(
            wqkv_bf + (size_t)l * MQKV * 160, xrT, 160, qkT, vF,
            nullptr, nullptr, nullptr, nullptr, nullptr, nullptr);
        attn_k2<<<1024, 256, 0, stream>>>(qkT, vF, oT);
        mgemm_k<160, 1, 2, 128><<<dim3(32, 6, 4), 256, 0, stream>>>(
            we_bf + (size_t)l * DD * 160, oT, 160, nullptr, nullptr,
            nullptr, nullptr, nullptr, nullptr, be[l], cols_f);
        fold_k<<<2048, 256, 0, stream>>>(cols_f, tin, touts[l]);
        tin = touts[l];
    }
    conv_k<<<512, 256, 0, stream>>>(tA, cw, cb, x, out);
}